// Round 1
// baseline (2380.728 us; speedup 1.0000x reference)
//
#include <hip/hip_runtime.h>
#include <math.h>

// Shapes (fixed by the problem)
//   L=1024 B=2 F=1024 E=2 H=2048 N=16 R=64 K=4, M = L*B = 2048 token rows.
// Pipeline:
//   G1: h = x @ W_in            (2048x1024x4096), epilogue splits xs/res
//   G2: conv-as-GEMM            (2048x2048, Kdim=4096) A-gather w/ row shift,
//       epilogue +b_conv, silu -> u
//   G3: proj = u @ W_ssm        (2048x2048x96)
//   G4: delta = softplus(dtraw @ W_dt + b_dt) clip[1e-3,0.1]  (Kdim=64)
//   S : selective scan, fused  y = scan + u*D;  z = y * silu(res)
//   G5: out = z @ W_out         (2048x2048x1024)

#define TILE 128
#define KT 16

template<int MODE>
__global__ __launch_bounds__(256) void gemm_k(
    const float* __restrict__ A, int lda,
    const float* __restrict__ B, int ldb,
    float* __restrict__ C, int ldc,
    int N, int K,
    const float* __restrict__ bias,
    float* __restrict__ C2)
{
    // MODE 0: plain   MODE 1: split xs/res   MODE 2: conv gather + bias + silu
    // MODE 3: bias + softplus + clip
    __shared__ float As[KT][TILE + 4];   // As[k][m], stride 132 floats (16B aligned)
    __shared__ float Bs[KT][TILE + 4];   // Bs[k][n]

    const int tid = threadIdx.x;
    const int tx = tid & 15;             // col group (8 cols each)
    const int ty = tid >> 4;             // row group (8 rows each)
    const int bm = blockIdx.y * TILE;
    const int bn = blockIdx.x * TILE;

    float acc[8][8];
#pragma unroll
    for (int i = 0; i < 8; ++i)
#pragma unroll
        for (int j = 0; j < 8; ++j) acc[i][j] = 0.f;

    const int a_c4 = tid & 3;            // float4 col within K-tile (0..3)
    const int a_r  = tid >> 2;           // 0..63
    const int b_c4 = tid & 31;           // float4 col within N-tile (0..31)
    const int b_r  = tid >> 5;           // 0..7

    int gofs = 0;
    if (MODE == 2) gofs = (bn >= 1024) ? 1024 : 0;  // conv group column offset

    for (int k0 = 0; k0 < K; k0 += KT) {
        // ---- A tile: 128 rows x 16 cols, float4 global loads, transposed LDS store
#pragma unroll
        for (int p = 0; p < 2; ++p) {
            int row = a_r + p * 64;          // 0..127
            int gm  = bm + row;              // M == 2048 exactly, no guard
            int gk  = k0 + a_c4 * 4;
            float4 v = make_float4(0.f, 0.f, 0.f, 0.f);
            if (MODE == 2) {
                int kk   = gk >> 10;         // conv tap 0..3
                int cc   = gk & 1023;        // channel within group
                int rowp = gm + 2 * kk - 6;  // m + B*(k-3), causal zero-pad
                if (rowp >= 0)
                    v = *(const float4*)(A + (size_t)rowp * lda + gofs + cc);
            } else {
                v = *(const float4*)(A + (size_t)gm * lda + gk);
            }
            int c = a_c4 * 4;
            As[c + 0][row] = v.x;
            As[c + 1][row] = v.y;
            As[c + 2][row] = v.z;
            As[c + 3][row] = v.w;
        }
        // ---- B tile: 16 rows x 128 cols
#pragma unroll
        for (int p = 0; p < 2; ++p) {
            int row = b_r + p * 8;           // 0..15
            int gk  = k0 + row;              // K always multiple of 16, no guard
            int gn  = bn + b_c4 * 4;
            float4 v = make_float4(0.f, 0.f, 0.f, 0.f);
            if (gn < N)                      // only partial for N=96
                v = *(const float4*)(B + (size_t)gk * ldb + gn);
            *(float4*)&Bs[row][b_c4 * 4] = v;
        }
        __syncthreads();

#pragma unroll
        for (int k = 0; k < KT; ++k) {
            float4 a0 = *(const float4*)&As[k][ty * 8];
            float4 a1 = *(const float4*)&As[k][ty * 8 + 4];
            float4 b0 = *(const float4*)&Bs[k][tx * 8];
            float4 b1 = *(const float4*)&Bs[k][tx * 8 + 4];
            float av[8] = {a0.x, a0.y, a0.z, a0.w, a1.x, a1.y, a1.z, a1.w};
            float bv[8] = {b0.x, b0.y, b0.z, b0.w, b1.x, b1.y, b1.z, b1.w};
#pragma unroll
            for (int i = 0; i < 8; ++i)
#pragma unroll
                for (int j = 0; j < 8; ++j)
                    acc[i][j] = fmaf(av[i], bv[j], acc[i][j]);
        }
        __syncthreads();
    }

    // ---- epilogue
#pragma unroll
    for (int i = 0; i < 8; ++i) {
        int gm = bm + ty * 8 + i;
#pragma unroll
        for (int jj = 0; jj < 2; ++jj) {
            int gn = bn + tx * 8 + jj * 4;
            if (gn >= N) continue;
            float t[4];
#pragma unroll
            for (int q = 0; q < 4; ++q) {
                float v = acc[i][jj * 4 + q];
                if (MODE == 2) {
                    v += bias[gn + q];
                    v = v / (1.f + __expf(-v));          // silu
                } else if (MODE == 3) {
                    v += bias[gn + q];
                    v = (v > 15.f) ? v : log1pf(__expf(v));  // softplus
                    v = fminf(fmaxf(v, 0.001f), 0.1f);       // clip
                }
                t[q] = v;
            }
            float4 v4 = make_float4(t[0], t[1], t[2], t[3]);
            if (MODE == 1) {
                if (gn < 2048)
                    *(float4*)(C + (size_t)gm * 2048 + gn) = v4;
                else
                    *(float4*)(C2 + (size_t)gm * 2048 + (gn - 2048)) = v4;
            } else {
                *(float4*)(C + (size_t)gm * ldc + gn) = v4;
            }
        }
    }
}

// Selective scan: one lane per (b,h,n). 65536 lanes, n fastest (16-lane groups).
// s_l = exp(dt*A)*s_{l-1} + (dt*u)*B ; y_l = sum_n C*s + u*D ; z = y*silu(res)
__global__ __launch_bounds__(256) void scan_k(
    const float* __restrict__ delta,   // [M][2048] (pre-clipped)
    const float* __restrict__ u,       // [M][2048]
    const float* __restrict__ proj,    // [M][96]  (B | C | dtraw)
    const float* __restrict__ A_log,   // [2048][16]
    const float* __restrict__ Dvec,    // [2048]
    const float* __restrict__ res,     // [M][2048]
    float* __restrict__ z)             // [M][2048]
{
    int g = blockIdx.x * 256 + threadIdx.x;  // 0..65535
    int n = g & 15;
    int h = (g >> 4) & 2047;
    int b = g >> 15;

    float Ahn = -__expf(A_log[h * 16 + n]);
    float Dh  = Dvec[h];
    float s = 0.f;

    for (int l = 0; l < 1024; ++l) {
        int m = l * 2 + b;
        float dt = delta[(size_t)m * 2048 + h];
        float uu = u[(size_t)m * 2048 + h];
        float Bm = proj[(size_t)m * 96 + n];
        float Cm = proj[(size_t)m * 96 + 16 + n];
        float dA = __expf(dt * Ahn);
        s = fmaf(dA, s, dt * uu * Bm);
        float val = Cm * s;
        val += __shfl_xor(val, 1, 16);
        val += __shfl_xor(val, 2, 16);
        val += __shfl_xor(val, 4, 16);
        val += __shfl_xor(val, 8, 16);
        if (n == 0) {
            float y = val + uu * Dh;
            float r = res[(size_t)m * 2048 + h];
            float sig = 1.f / (1.f + __expf(-r));
            z[(size_t)m * 2048 + h] = y * (r * sig);
        }
    }
}

extern "C" void kernel_launch(void* const* d_in, const int* in_sizes, int n_in,
                              void* d_out, int out_size, void* d_ws, size_t ws_size,
                              hipStream_t stream)
{
    const float* x      = (const float*)d_in[0];
    const float* W_in   = (const float*)d_in[1];
    const float* W_conv = (const float*)d_in[2];
    const float* b_conv = (const float*)d_in[3];
    const float* A_log  = (const float*)d_in[4];
    const float* Dv     = (const float*)d_in[5];
    const float* W_ssm  = (const float*)d_in[6];
    const float* W_dt   = (const float*)d_in[7];
    const float* b_dt   = (const float*)d_in[8];
    const float* W_out  = (const float*)d_in[9];
    float* out = (float*)d_out;

    float* ws      = (float*)d_ws;
    float* xsbuf   = ws;                         // 2048*2048; reused as z after conv
    float* resbuf  = xsbuf  + 2048 * 2048;       // 2048*2048
    float* ubuf    = resbuf + 2048 * 2048;       // 2048*2048
    float* projbuf = ubuf   + 2048 * 2048;       // 2048*96
    float* deltab  = projbuf + 2048 * 96;        // 2048*2048
    // total: 67.9 MB of d_ws

    dim3 blk(256);

    // G1: h = x @ W_in -> xs | res
    gemm_k<1><<<dim3(4096 / TILE, 2048 / TILE), blk, 0, stream>>>(
        x, 1024, W_in, 4096, xsbuf, 0, 4096, 1024, nullptr, resbuf);

    // G2: grouped causal conv as gather-GEMM, +b_conv, silu -> u
    gemm_k<2><<<dim3(2048 / TILE, 2048 / TILE), blk, 0, stream>>>(
        xsbuf, 2048, W_conv, 2048, ubuf, 2048, 2048, 4096, b_conv, nullptr);

    // G3: proj = u @ W_ssm  (N=96)
    gemm_k<0><<<dim3(1, 2048 / TILE), blk, 0, stream>>>(
        ubuf, 2048, W_ssm, 96, projbuf, 96, 96, 2048, nullptr, nullptr);

    // G4: delta = clip(softplus(dtraw @ W_dt + b_dt))
    gemm_k<3><<<dim3(2048 / TILE, 2048 / TILE), blk, 0, stream>>>(
        projbuf + 32, 96, W_dt, 2048, deltab, 2048, 2048, 64, b_dt, nullptr);

    // S: selective scan -> z (reuses xsbuf)
    scan_k<<<dim3(256), blk, 0, stream>>>(
        deltab, ubuf, projbuf, A_log, Dv, resbuf, xsbuf);

    // G5: out = z @ W_out
    gemm_k<0><<<dim3(1024 / TILE, 2048 / TILE), blk, 0, stream>>>(
        xsbuf, 2048, W_out, 1024, out, 1024, 1024, 2048, nullptr, nullptr);
}

// Round 2
// 1294.363 us; speedup vs baseline: 1.8393x; 1.8393x over previous
//
#include <hip/hip_runtime.h>
#include <math.h>

// L=1024 B=2 F=1024 E=2 H=2048 N=16 R=64 K=4, M=2048 token rows.
//   T : W_conv fp32 [4096][2048] -> WT bf16 [2048][4096] (transpose+convert)
//   G1: h = x @ W_in (fp32 vector GEMM), epilogue -> xs (bf16), res (fp32)
//   C : conv-as-GEMM, bf16 MFMA 16x16x32, tile 128x64, epilogue silu -> u (fp32)
//   G3: proj = u @ W_ssm (fp32)
//   G4: delta = clip(softplus(dtraw @ W_dt + b_dt)) (fp32)
//   S : chunked selective scan (16 chunks of 64), fused epilogue -> z (aliases delta)
//   G5: out = z @ W_out (fp32)

typedef unsigned short u16;
typedef __attribute__((ext_vector_type(8))) short short8;
typedef __attribute__((ext_vector_type(4))) float floatx4;
typedef __attribute__((ext_vector_type(4))) unsigned short ushort4v;

__device__ __forceinline__ u16 f2bf(float f) {
    unsigned int u = __float_as_uint(f);
    unsigned int r = (u + 0x7fffu + ((u >> 16) & 1u)) >> 16;
    return (u16)r;
}

#define TILE 128
#define KT 16

// ---------------- fp32 tiled GEMM (modes 0/1/3) ----------------
template<int MODE>
__global__ __launch_bounds__(256) void gemm_k(
    const float* __restrict__ A, int lda,
    const float* __restrict__ B, int ldb,
    float* __restrict__ C, int ldc,
    int N, int K,
    const float* __restrict__ bias,
    float* __restrict__ C2,
    u16* __restrict__ Cb)
{
    // MODE 0: plain   MODE 1: split xs(bf16)/res(fp32)   MODE 3: bias+softplus+clip
    __shared__ float As[KT][TILE + 4];
    __shared__ float Bs[KT][TILE + 4];

    const int tid = threadIdx.x;
    const int tx = tid & 15;
    const int ty = tid >> 4;
    const int bm = blockIdx.y * TILE;
    const int bn = blockIdx.x * TILE;

    float acc[8][8];
#pragma unroll
    for (int i = 0; i < 8; ++i)
#pragma unroll
        for (int j = 0; j < 8; ++j) acc[i][j] = 0.f;

    const int a_c4 = tid & 3;
    const int a_r  = tid >> 2;
    const int b_c4 = tid & 31;
    const int b_r  = tid >> 5;

    for (int k0 = 0; k0 < K; k0 += KT) {
#pragma unroll
        for (int p = 0; p < 2; ++p) {
            int row = a_r + p * 64;
            int gm  = bm + row;
            int gk  = k0 + a_c4 * 4;
            float4 v = *(const float4*)(A + (size_t)gm * lda + gk);
            int c = a_c4 * 4;
            As[c + 0][row] = v.x;
            As[c + 1][row] = v.y;
            As[c + 2][row] = v.z;
            As[c + 3][row] = v.w;
        }
#pragma unroll
        for (int p = 0; p < 2; ++p) {
            int row = b_r + p * 8;
            int gk  = k0 + row;
            int gn  = bn + b_c4 * 4;
            float4 v = make_float4(0.f, 0.f, 0.f, 0.f);
            if (gn < N)
                v = *(const float4*)(B + (size_t)gk * ldb + gn);
            *(float4*)&Bs[row][b_c4 * 4] = v;
        }
        __syncthreads();

#pragma unroll
        for (int k = 0; k < KT; ++k) {
            float4 a0 = *(const float4*)&As[k][ty * 8];
            float4 a1 = *(const float4*)&As[k][ty * 8 + 4];
            float4 b0 = *(const float4*)&Bs[k][tx * 8];
            float4 b1 = *(const float4*)&Bs[k][tx * 8 + 4];
            float av[8] = {a0.x, a0.y, a0.z, a0.w, a1.x, a1.y, a1.z, a1.w};
            float bv[8] = {b0.x, b0.y, b0.z, b0.w, b1.x, b1.y, b1.z, b1.w};
#pragma unroll
            for (int i = 0; i < 8; ++i)
#pragma unroll
                for (int j = 0; j < 8; ++j)
                    acc[i][j] = fmaf(av[i], bv[j], acc[i][j]);
        }
        __syncthreads();
    }

#pragma unroll
    for (int i = 0; i < 8; ++i) {
        int gm = bm + ty * 8 + i;
#pragma unroll
        for (int jj = 0; jj < 2; ++jj) {
            int gn = bn + tx * 8 + jj * 4;
            if (gn >= N) continue;
            float t[4];
#pragma unroll
            for (int q = 0; q < 4; ++q) {
                float v = acc[i][jj * 4 + q];
                if (MODE == 3) {
                    v += bias[gn + q];
                    v = (v > 15.f) ? v : log1pf(__expf(v));
                    v = fminf(fmaxf(v, 0.001f), 0.1f);
                }
                t[q] = v;
            }
            if (MODE == 1) {
                if (gn < 2048) {
                    ushort4v h;
                    h.x = f2bf(t[0]); h.y = f2bf(t[1]);
                    h.z = f2bf(t[2]); h.w = f2bf(t[3]);
                    *(ushort4v*)(Cb + (size_t)gm * 2048 + gn) = h;
                } else {
                    *(float4*)(C2 + (size_t)gm * 2048 + (gn - 2048)) =
                        make_float4(t[0], t[1], t[2], t[3]);
                }
            } else {
                *(float4*)(C + (size_t)gm * ldc + gn) =
                    make_float4(t[0], t[1], t[2], t[3]);
            }
        }
    }
}

// ---------------- W_conv transpose + bf16 convert ----------------
__global__ __launch_bounds__(256) void wconv_t_k(const float* __restrict__ W,
                                                 u16* __restrict__ WT)
{
    __shared__ u16 t[64][65];
    int bk = blockIdx.x * 64;   // k (0..4095)
    int bh = blockIdx.y * 64;   // h (0..2047)
    int c = threadIdx.x & 63;
    int r0 = threadIdx.x >> 6;  // 0..3
#pragma unroll
    for (int i = 0; i < 16; ++i) {
        int r = r0 + i * 4;
        t[r][c] = f2bf(W[(size_t)(bk + r) * 2048 + bh + c]);
    }
    __syncthreads();
#pragma unroll
    for (int i = 0; i < 16; ++i) {
        int r = r0 + i * 4;
        WT[(size_t)(bh + r) * 4096 + bk + c] = t[c][r];
    }
}

// ---------------- conv as bf16 MFMA GEMM ----------------
// A (gathered xs_bf16) [2048 m][4096 k], k=(tap,chan); B = WT [2048 h][4096 k].
// Tile 128m x 64n, BK=32 (one tap per K-tile since 1024%32==0 -> uniform shift).
#define APAD 40

__global__ __launch_bounds__(256) void conv_mfma_k(
    const u16* __restrict__ xsb,   // [2048][2048] bf16
    const u16* __restrict__ WT,    // [2048][4096] bf16
    const float* __restrict__ b_conv,
    float* __restrict__ u)         // [2048][2048] fp32
{
    __shared__ u16 As[128 * APAD];
    __shared__ u16 Bs[64 * APAD];

    const int tid = threadIdx.x;
    const int bm = blockIdx.y * 128;
    const int bn = blockIdx.x * 64;
    const int gofs = (bn >= 1024) ? 1024 : 0;
    const int lane = tid & 63;
    const int wave = tid >> 6;
    const int wm = wave * 32;
    const int m16 = lane & 15;
    const int q   = lane >> 4;

    floatx4 acc[2][4] = {};

    const int ar = tid >> 2;        // staging row 0..63
    const int ac = (tid & 3) * 8;   // staging bf16 col

    for (int kt = 0; kt < 128; ++kt) {
        const int k0 = kt * 32;
        const int kk = k0 >> 10;          // conv tap
        const int ck = k0 & 1023;         // channel base within group
#pragma unroll
        for (int p = 0; p < 2; ++p) {
            int r  = ar + p * 64;
            int rg = bm + r + 2 * kk - 6; // causal shift, uniform per tile
            short8 v = {};
            if (rg >= 0)
                v = *(const short8*)(xsb + (size_t)rg * 2048 + gofs + ck + ac);
            *(short8*)(As + r * APAD + ac) = v;
        }
        {
            short8 v = *(const short8*)(WT + (size_t)(bn + ar) * 4096 + k0 + ac);
            *(short8*)(Bs + ar * APAD + ac) = v;
        }
        __syncthreads();

        short8 af[2], bf[4];
#pragma unroll
        for (int ti = 0; ti < 2; ++ti)
            af[ti] = *(const short8*)(As + (wm + ti * 16 + m16) * APAD + q * 8);
#pragma unroll
        for (int tj = 0; tj < 4; ++tj)
            bf[tj] = *(const short8*)(Bs + (tj * 16 + m16) * APAD + q * 8);
#pragma unroll
        for (int ti = 0; ti < 2; ++ti)
#pragma unroll
            for (int tj = 0; tj < 4; ++tj)
                acc[ti][tj] = __builtin_amdgcn_mfma_f32_16x16x32_bf16(
                    af[ti], bf[tj], acc[ti][tj], 0, 0, 0);
        __syncthreads();
    }

    // epilogue: +bias, silu -> u   (D: col=lane&15, row=q*4+reg)
#pragma unroll
    for (int tj = 0; tj < 4; ++tj) {
        int gn = bn + tj * 16 + m16;
        float bias = b_conv[gn];
#pragma unroll
        for (int ti = 0; ti < 2; ++ti) {
#pragma unroll
            for (int r = 0; r < 4; ++r) {
                int gm = bm + wm + ti * 16 + q * 4 + r;
                float v = acc[ti][tj][r] + bias;
                v = v / (1.f + __expf(-v));
                u[(size_t)gm * 2048 + gn] = v;
            }
        }
    }
}

// ---------------- chunked selective scan ----------------
// Block per (b,h); tid = c*16+n, 16 chunks of 64 steps.
__global__ __launch_bounds__(256) void scan2_k(
    const float* delta,               // [2048][2048] -- ALIASES z
    const float* __restrict__ u,
    const float* __restrict__ proj,   // [2048][96] (B|C|dtraw)
    const float* __restrict__ A_log,  // [2048][16]
    const float* __restrict__ Dvec,
    const float* __restrict__ res,
    float* z)
{
    __shared__ float lP[16][16], lS[16][16], lI[16][16];
    const int h = blockIdx.x & 2047;
    const int b = blockIdx.x >> 11;
    const int tid = threadIdx.x;
    const int n = tid & 15;
    const int c = tid >> 4;
    const int l0 = c * 64;

    const float Ahn = -__expf(A_log[h * 16 + n]);

    float s = 0.f, P = 1.f;
    for (int j = 0; j < 64; ++j) {
        int m = (l0 + j) * 2 + b;
        float dt = delta[(size_t)m * 2048 + h];
        float uu = u[(size_t)m * 2048 + h];
        float Bm = proj[(size_t)m * 96 + n];
        float dA = __expf(dt * Ahn);
        s = fmaf(dA, s, dt * uu * Bm);
        P *= dA;
    }
    lP[c][n] = P;
    lS[c][n] = s;
    __syncthreads();
    if (tid < 16) {   // serial combine over 16 chunk summaries, one thread per n
        float X = 0.f;
#pragma unroll
        for (int cc = 0; cc < 16; ++cc) {
            lI[cc][tid] = X;
            X = fmaf(lP[cc][tid], X, lS[cc][tid]);
        }
    }
    __syncthreads();

    s = lI[c][n];
    const float Dh = Dvec[h];
    for (int j = 0; j < 64; ++j) {
        int m = (l0 + j) * 2 + b;
        float dt = delta[(size_t)m * 2048 + h];
        float uu = u[(size_t)m * 2048 + h];
        float Bm = proj[(size_t)m * 96 + n];
        float Cm = proj[(size_t)m * 96 + 16 + n];
        float dA = __expf(dt * Ahn);
        s = fmaf(dA, s, dt * uu * Bm);
        float val = Cm * s;
        val += __shfl_xor(val, 1, 16);
        val += __shfl_xor(val, 2, 16);
        val += __shfl_xor(val, 4, 16);
        val += __shfl_xor(val, 8, 16);
        if (n == 0) {
            float y = val + uu * Dh;
            float r = res[(size_t)m * 2048 + h];
            z[(size_t)m * 2048 + h] = y * (r / (1.f + __expf(-r)));
        }
    }
}

extern "C" void kernel_launch(void* const* d_in, const int* in_sizes, int n_in,
                              void* d_out, int out_size, void* d_ws, size_t ws_size,
                              hipStream_t stream)
{
    const float* x      = (const float*)d_in[0];
    const float* W_in   = (const float*)d_in[1];
    const float* W_conv = (const float*)d_in[2];
    const float* b_conv = (const float*)d_in[3];
    const float* A_log  = (const float*)d_in[4];
    const float* Dv     = (const float*)d_in[5];
    const float* W_ssm  = (const float*)d_in[6];
    const float* W_dt   = (const float*)d_in[7];
    const float* b_dt   = (const float*)d_in[8];
    const float* W_out  = (const float*)d_in[9];
    float* out = (float*)d_out;

    // ws layout (57 MB):
    //   xsbf   bf16 [2048][2048]   8 MB
    //   resbuf f32  [2048][2048]  16 MB
    //   ubuf   f32  [2048][2048]  16 MB
    //   projbuf f32 [2048][96]     1 MB (padded)
    //   ws4    16 MB: WT bf16 [2048][4096] (until conv done), then delta, then z
    char* wsc = (char*)d_ws;
    u16*   xsbf   = (u16*)wsc;
    float* resbuf = (float*)(wsc + (8u << 20));
    float* ubuf   = (float*)(wsc + (24u << 20));
    float* projbuf= (float*)(wsc + (40u << 20));
    char*  ws4    = wsc + (41u << 20);
    u16*   WT     = (u16*)ws4;
    float* deltab = (float*)ws4;   // overwrites WT after conv is done
    float* zbuf   = deltab;        // scan writes z in place of delta (safe, see scan2_k)

    dim3 blk(256);

    // T: W_conv -> WT (bf16, transposed)
    wconv_t_k<<<dim3(64, 32), blk, 0, stream>>>(W_conv, WT);

    // G1: h = x @ W_in -> xs(bf16) | res(fp32)
    gemm_k<1><<<dim3(32, 16), blk, 0, stream>>>(
        x, 1024, W_in, 4096, nullptr, 0, 4096, 1024, nullptr, resbuf, xsbf);

    // C: conv (bf16 MFMA) -> u
    conv_mfma_k<<<dim3(32, 16), blk, 0, stream>>>(xsbf, WT, b_conv, ubuf);

    // G3: proj = u @ W_ssm (N=96)
    gemm_k<0><<<dim3(1, 16), blk, 0, stream>>>(
        ubuf, 2048, W_ssm, 96, projbuf, 96, 96, 2048, nullptr, nullptr, nullptr);

    // G4: delta = clip(softplus(dtraw @ W_dt + b_dt))
    gemm_k<3><<<dim3(16, 16), blk, 0, stream>>>(
        projbuf + 32, 96, W_dt, 2048, deltab, 2048, 2048, 64, b_dt, nullptr, nullptr);

    // S: chunked scan -> z (in place of delta)
    scan2_k<<<dim3(4096), blk, 0, stream>>>(
        deltab, ubuf, projbuf, A_log, Dv, resbuf, zbuf);

    // G5: out = z @ W_out
    gemm_k<0><<<dim3(8, 16), blk, 0, stream>>>(
        zbuf, 2048, W_out, 1024, out, 1024, 1024, 2048, nullptr, nullptr, nullptr);
}

// Round 3
// 589.753 us; speedup vs baseline: 4.0368x; 2.1948x over previous
//
#include <hip/hip_runtime.h>
#include <math.h>

// L=1024 B=2 F=1024 E=2 H=2048 N=16 R=64 K=4, M=2048 rows.
// All big GEMMs are bf16 MFMA (16x16x32), tile 128m x 64n, BK=32, 256 thr.
//   T : transposes/converts: WT_in, WT_conv, WT_out, WT_ssm (bf16 [n][k]); xb = bf16(x)
//   G1: h = xb @ WT_in^T -> xs(bf16) | res(bf16)            (2048x4096x1024)
//   C : conv gather-GEMM  -> u(fp32), +bias, silu           (2048x2048x4096)
//   G3: proj = u @ W_ssm  split-K=4, atomicAdd fp32, ld 128 (2048x96x2048)
//   G4: delta = clip(softplus(dtraw @ W_dt + b_dt)) fp32    (K=64)
//   S : chunked scan (16x64) -> z (bf16)
//   G5: out = zb @ WT_out^T (fp32 out)                      (2048x1024x2048)

typedef unsigned short u16;
typedef unsigned int u32;
typedef __attribute__((ext_vector_type(8))) short short8;
typedef __attribute__((ext_vector_type(4))) float floatx4;

__device__ __forceinline__ u16 f2bf(float f) {
    u32 u = __float_as_uint(f);
    return (u16)((u + 0x7fffu + ((u >> 16) & 1u)) >> 16);
}
__device__ __forceinline__ float bf2f(u16 v) {
    return __uint_as_float((u32)v << 16);
}

#define APAD 40

// ---------------- generic fp32 -> bf16 transpose:  S[R][C] -> D[C][R] ----------------
__global__ __launch_bounds__(256) void trans_k(const float* __restrict__ S,
                                               u16* __restrict__ D, int R, int C)
{
    __shared__ u16 t[64][65];
    int br = blockIdx.x * 64;
    int bc = blockIdx.y * 64;
    int c = threadIdx.x & 63;
    int r0 = threadIdx.x >> 6;
#pragma unroll
    for (int i = 0; i < 16; ++i) {
        int r = r0 + i * 4;
        float v = 0.f;
        if (br + r < R && bc + c < C) v = S[(size_t)(br + r) * C + bc + c];
        t[r][c] = f2bf(v);
    }
    __syncthreads();
#pragma unroll
    for (int i = 0; i < 16; ++i) {
        int r = r0 + i * 4;
        if (bc + r < C && br + c < R)
            D[(size_t)(bc + r) * R + br + c] = t[c][r];
    }
}

// ---------------- x fp32 -> bf16 ----------------
__global__ __launch_bounds__(256) void cvt_k(const float* __restrict__ S, u16* __restrict__ D)
{
    int i = (blockIdx.x * 256 + threadIdx.x) * 4;
    float4 v = *(const float4*)(S + i);
    u16 o[4] = {f2bf(v.x), f2bf(v.y), f2bf(v.z), f2bf(v.w)};
    *(ulong1*)(D + i) = *(ulong1*)o;
}

// ---------------- bf16 MFMA GEMM: A[M][K] x B[N][K]^T, tile 128x64 ----------------
// MODE 0: G1 split xs/res (both bf16)   MODE 1: conv gather +bias+silu -> fp32
// MODE 2: plain fp32 out
template<int MODE>
__global__ __launch_bounds__(256) void mfma_k(
    const u16* __restrict__ A, int lda,
    const u16* __restrict__ B, int ldb,
    float* __restrict__ Cf, int ldc,
    u16* __restrict__ Cb0, u16* __restrict__ Cb1,
    const float* __restrict__ bias, int nkt)
{
    __shared__ u16 As[128 * APAD];
    __shared__ u16 Bs[64 * APAD];
    const int tid = threadIdx.x;
    const int bm = blockIdx.y * 128;
    const int bn = blockIdx.x * 64;
    const int gofs = (MODE == 1 && bn >= 1024) ? 1024 : 0;
    const int lane = tid & 63, wave = tid >> 6, wm = wave * 32;
    const int m16 = lane & 15, q = lane >> 4;
    floatx4 acc[2][4] = {};
    const int ar = tid >> 2, ac = (tid & 3) * 8;

    for (int kt = 0; kt < nkt; ++kt) {
        const int k0 = kt * 32;
#pragma unroll
        for (int p = 0; p < 2; ++p) {
            int r = ar + p * 64;
            short8 v = {};
            if (MODE == 1) {
                int kk = k0 >> 10, ck = k0 & 1023;
                int rg = bm + r + 2 * kk - 6;       // causal shift, tile-uniform
                if (rg >= 0)
                    v = *(const short8*)(A + (size_t)rg * lda + gofs + ck + ac);
            } else {
                v = *(const short8*)(A + (size_t)(bm + r) * lda + k0 + ac);
            }
            *(short8*)(As + r * APAD + ac) = v;
        }
        *(short8*)(Bs + ar * APAD + ac) =
            *(const short8*)(B + (size_t)(bn + ar) * ldb + k0 + ac);
        __syncthreads();

        short8 af[2], bfr[4];
#pragma unroll
        for (int ti = 0; ti < 2; ++ti)
            af[ti] = *(const short8*)(As + (wm + ti * 16 + m16) * APAD + q * 8);
#pragma unroll
        for (int tj = 0; tj < 4; ++tj)
            bfr[tj] = *(const short8*)(Bs + (tj * 16 + m16) * APAD + q * 8);
#pragma unroll
        for (int ti = 0; ti < 2; ++ti)
#pragma unroll
            for (int tj = 0; tj < 4; ++tj)
                acc[ti][tj] = __builtin_amdgcn_mfma_f32_16x16x32_bf16(
                    af[ti], bfr[tj], acc[ti][tj], 0, 0, 0);
        __syncthreads();
    }

#pragma unroll
    for (int tj = 0; tj < 4; ++tj) {
        int gn = bn + tj * 16 + m16;
        float bv = (MODE == 1) ? bias[gn] : 0.f;
#pragma unroll
        for (int ti = 0; ti < 2; ++ti)
#pragma unroll
            for (int r = 0; r < 4; ++r) {
                int gm = bm + wm + ti * 16 + q * 4 + r;
                float v = acc[ti][tj][r];
                if (MODE == 0) {
                    if (gn < 2048) Cb0[(size_t)gm * 2048 + gn] = f2bf(v);
                    else           Cb1[(size_t)gm * 2048 + gn - 2048] = f2bf(v);
                } else if (MODE == 1) {
                    v += bv;
                    v = v / (1.f + __expf(-v));
                    Cf[(size_t)gm * ldc + gn] = v;
                } else {
                    Cf[(size_t)gm * ldc + gn] = v;
                }
            }
    }
}

// ---------------- G3: proj = u @ W_ssm, split-K MFMA with fp32 atomics ----------------
__global__ __launch_bounds__(256) void g3_k(
    const float* __restrict__ U,    // [2048][2048] fp32
    const u16* __restrict__ Bw,     // WT_ssm [128][2048] bf16 (rows 96+ junk, unread cols)
    float* __restrict__ proj)       // [2048][128] fp32, pre-zeroed
{
    __shared__ u16 As[128 * APAD];
    __shared__ u16 Bs[64 * APAD];
    const int tid = threadIdx.x;
    const int bn = blockIdx.x * 64;
    const int bm = blockIdx.y * 128;
    const int kb = blockIdx.z * 512;
    const int lane = tid & 63, wave = tid >> 6, wm = wave * 32;
    const int m16 = lane & 15, q = lane >> 4;
    floatx4 acc[2][4] = {};
    const int ar = tid >> 2, ac = (tid & 3) * 8;

    for (int kt = 0; kt < 16; ++kt) {
        const int k0 = kb + kt * 32;
#pragma unroll
        for (int p = 0; p < 2; ++p) {
            int r = ar + p * 64;
            const float* src = U + (size_t)(bm + r) * 2048 + k0 + ac;
            float4 v0 = *(const float4*)src;
            float4 v1 = *(const float4*)(src + 4);
            short8 v = {(short)f2bf(v0.x), (short)f2bf(v0.y), (short)f2bf(v0.z),
                        (short)f2bf(v0.w), (short)f2bf(v1.x), (short)f2bf(v1.y),
                        (short)f2bf(v1.z), (short)f2bf(v1.w)};
            *(short8*)(As + r * APAD + ac) = v;
        }
        *(short8*)(Bs + ar * APAD + ac) =
            *(const short8*)(Bw + (size_t)(bn + ar) * 2048 + k0 + ac);
        __syncthreads();

        short8 af[2], bfr[4];
#pragma unroll
        for (int ti = 0; ti < 2; ++ti)
            af[ti] = *(const short8*)(As + (wm + ti * 16 + m16) * APAD + q * 8);
#pragma unroll
        for (int tj = 0; tj < 4; ++tj)
            bfr[tj] = *(const short8*)(Bs + (tj * 16 + m16) * APAD + q * 8);
#pragma unroll
        for (int ti = 0; ti < 2; ++ti)
#pragma unroll
            for (int tj = 0; tj < 4; ++tj)
                acc[ti][tj] = __builtin_amdgcn_mfma_f32_16x16x32_bf16(
                    af[ti], bfr[tj], acc[ti][tj], 0, 0, 0);
        __syncthreads();
    }

#pragma unroll
    for (int tj = 0; tj < 4; ++tj) {
        int gn = bn + tj * 16 + m16;
#pragma unroll
        for (int ti = 0; ti < 2; ++ti)
#pragma unroll
            for (int r = 0; r < 4; ++r) {
                int gm = bm + wm + ti * 16 + q * 4 + r;
                atomicAdd(proj + (size_t)gm * 128 + gn, acc[ti][tj][r]);
            }
    }
}

// ---------------- G4: delta = clip(softplus(dtraw @ W_dt + b_dt)), fp32 ----------------
__global__ __launch_bounds__(256) void g4_k(
    const float* __restrict__ A,   // proj+32, lda=128
    const float* __restrict__ B,   // W_dt [64][2048]
    const float* __restrict__ bias,
    float* __restrict__ C)         // delta [2048][2048]
{
    __shared__ float As[16][132];
    __shared__ float Bs[16][132];
    const int tid = threadIdx.x;
    const int tx = tid & 15, ty = tid >> 4;
    const int bm = blockIdx.y * 128, bn = blockIdx.x * 128;
    float acc[8][8] = {};
    const int a_c4 = tid & 3, a_r = tid >> 2;
    const int b_c4 = tid & 31, b_r = tid >> 5;

    for (int k0 = 0; k0 < 64; k0 += 16) {
#pragma unroll
        for (int p = 0; p < 2; ++p) {
            int row = a_r + p * 64;
            float4 v = *(const float4*)(A + (size_t)(bm + row) * 128 + k0 + a_c4 * 4);
            int c = a_c4 * 4;
            As[c + 0][row] = v.x; As[c + 1][row] = v.y;
            As[c + 2][row] = v.z; As[c + 3][row] = v.w;
        }
#pragma unroll
        for (int p = 0; p < 2; ++p) {
            int row = b_r + p * 8;
            *(float4*)&Bs[row][b_c4 * 4] =
                *(const float4*)(B + (size_t)(k0 + row) * 2048 + bn + b_c4 * 4);
        }
        __syncthreads();
#pragma unroll
        for (int k = 0; k < 16; ++k) {
            float4 a0 = *(const float4*)&As[k][ty * 8];
            float4 a1 = *(const float4*)&As[k][ty * 8 + 4];
            float4 b0 = *(const float4*)&Bs[k][tx * 8];
            float4 b1 = *(const float4*)&Bs[k][tx * 8 + 4];
            float av[8] = {a0.x, a0.y, a0.z, a0.w, a1.x, a1.y, a1.z, a1.w};
            float bv[8] = {b0.x, b0.y, b0.z, b0.w, b1.x, b1.y, b1.z, b1.w};
#pragma unroll
            for (int i = 0; i < 8; ++i)
#pragma unroll
                for (int j = 0; j < 8; ++j)
                    acc[i][j] = fmaf(av[i], bv[j], acc[i][j]);
        }
        __syncthreads();
    }
#pragma unroll
    for (int i = 0; i < 8; ++i) {
        int gm = bm + ty * 8 + i;
#pragma unroll
        for (int jj = 0; jj < 2; ++jj) {
            int gn = bn + tx * 8 + jj * 4;
            float t[4];
#pragma unroll
            for (int qq = 0; qq < 4; ++qq) {
                float v = acc[i][jj * 4 + qq] + bias[gn + qq];
                v = (v > 15.f) ? v : log1pf(__expf(v));
                t[qq] = fminf(fmaxf(v, 0.001f), 0.1f);
            }
            *(float4*)(C + (size_t)gm * 2048 + gn) = make_float4(t[0], t[1], t[2], t[3]);
        }
    }
}

// ---------------- chunked selective scan ----------------
__global__ __launch_bounds__(256) void scan2_k(
    const float* __restrict__ delta,   // [2048][2048]
    const float* __restrict__ u,       // [2048][2048]
    const float* __restrict__ proj,    // [2048][128] (B|C|dtraw|pad)
    const float* __restrict__ A_log,
    const float* __restrict__ Dvec,
    const u16* __restrict__ resb,      // [2048][2048] bf16
    u16* __restrict__ zb)              // [2048][2048] bf16
{
    __shared__ float lP[16][16], lS[16][16], lI[16][16];
    const int h = blockIdx.x & 2047;
    const int b = blockIdx.x >> 11;
    const int tid = threadIdx.x;
    const int n = tid & 15;
    const int c = tid >> 4;
    const int l0 = c * 64;

    const float Ahn = -__expf(A_log[h * 16 + n]);

    float s = 0.f, P = 1.f;
    for (int j = 0; j < 64; ++j) {
        int m = (l0 + j) * 2 + b;
        float dt = delta[(size_t)m * 2048 + h];
        float uu = u[(size_t)m * 2048 + h];
        float Bm = proj[(size_t)m * 128 + n];
        float dA = __expf(dt * Ahn);
        s = fmaf(dA, s, dt * uu * Bm);
        P *= dA;
    }
    lP[c][n] = P;
    lS[c][n] = s;
    __syncthreads();
    if (tid < 16) {
        float X = 0.f;
#pragma unroll
        for (int cc = 0; cc < 16; ++cc) {
            lI[cc][tid] = X;
            X = fmaf(lP[cc][tid], X, lS[cc][tid]);
        }
    }
    __syncthreads();

    s = lI[c][n];
    const float Dh = Dvec[h];
    for (int j = 0; j < 64; ++j) {
        int m = (l0 + j) * 2 + b;
        float dt = delta[(size_t)m * 2048 + h];
        float uu = u[(size_t)m * 2048 + h];
        float Bm = proj[(size_t)m * 128 + n];
        float Cm = proj[(size_t)m * 128 + 16 + n];
        float dA = __expf(dt * Ahn);
        s = fmaf(dA, s, dt * uu * Bm);
        float val = Cm * s;
        val += __shfl_xor(val, 1, 16);
        val += __shfl_xor(val, 2, 16);
        val += __shfl_xor(val, 4, 16);
        val += __shfl_xor(val, 8, 16);
        if (n == 0) {
            float y = val + uu * Dh;
            float r = bf2f(resb[(size_t)m * 2048 + h]);
            zb[(size_t)m * 2048 + h] = f2bf(y * (r / (1.f + __expf(-r))));
        }
    }
}

extern "C" void kernel_launch(void* const* d_in, const int* in_sizes, int n_in,
                              void* d_out, int out_size, void* d_ws, size_t ws_size,
                              hipStream_t stream)
{
    const float* x      = (const float*)d_in[0];
    const float* W_in   = (const float*)d_in[1];
    const float* W_conv = (const float*)d_in[2];
    const float* b_conv = (const float*)d_in[3];
    const float* A_log  = (const float*)d_in[4];
    const float* Dv     = (const float*)d_in[5];
    const float* W_ssm  = (const float*)d_in[6];
    const float* W_dt   = (const float*)d_in[7];
    const float* b_dt   = (const float*)d_in[8];
    const float* W_out  = (const float*)d_in[9];
    float* out = (float*)d_out;

    // ws layout (64.5 MB), lifetime-aliased:
    //  off  0M: xb bf16 [2048][1024] (T..G1)   -> proj fp32 [2048][128] (G3..scan)
    //  off  4M: WT_in bf16 [4096][1024] (T..G1)
    //  off 12M: xsbf bf16 [2048][2048] (G1..conv) -> zb bf16 (scan..G5)
    //  off 20M: resb bf16 [2048][2048] (G1..scan)
    //  off 28M: WT_conv bf16 [2048][4096] (T..conv) -> delta fp32 [2048][2048] (G4..scan)
    //  off 44M: u fp32 [2048][2048] (conv..scan)
    //  off 60M: WT_out bf16 [1024][2048] (T..G5)
    //  off 64M: WT_ssm bf16 [128][2048] (T..G3)
    char* wsc = (char*)d_ws;
    u16*   xb     = (u16*)wsc;
    float* projb  = (float*)wsc;
    u16*   WT_in  = (u16*)(wsc + (4u << 20));
    u16*   xsbf   = (u16*)(wsc + (12u << 20));
    u16*   zb     = xsbf;
    u16*   resb   = (u16*)(wsc + (20u << 20));
    u16*   WT_cv  = (u16*)(wsc + (28u << 20));
    float* deltab = (float*)(wsc + (28u << 20));
    float* ubuf   = (float*)(wsc + (44u << 20));
    u16*   WT_out = (u16*)(wsc + (60u << 20));
    u16*   WT_ssm = (u16*)(wsc + (64u << 20));

    dim3 blk(256);

    // T: transposes + convert
    trans_k<<<dim3(64, 32), blk, 0, stream>>>(W_conv, WT_cv, 4096, 2048);
    trans_k<<<dim3(16, 64), blk, 0, stream>>>(W_in, WT_in, 1024, 4096);
    trans_k<<<dim3(32, 16), blk, 0, stream>>>(W_out, WT_out, 2048, 1024);
    trans_k<<<dim3(32, 2),  blk, 0, stream>>>(W_ssm, WT_ssm, 2048, 96);
    cvt_k<<<dim3(2048), blk, 0, stream>>>(x, xb);

    // G1: xs | res
    mfma_k<0><<<dim3(64, 16), blk, 0, stream>>>(
        xb, 1024, WT_in, 1024, nullptr, 0, xsbf, resb, nullptr, 32);

    // C: conv -> u
    mfma_k<1><<<dim3(32, 16), blk, 0, stream>>>(
        xsbf, 2048, WT_cv, 4096, ubuf, 2048, nullptr, nullptr, b_conv, 128);

    // G3: proj (split-K atomics)
    hipMemsetAsync(projb, 0, 2048 * 128 * sizeof(float), stream);
    g3_k<<<dim3(2, 16, 4), blk, 0, stream>>>(ubuf, WT_ssm, projb);

    // G4: delta
    g4_k<<<dim3(16, 16), blk, 0, stream>>>(projb + 32, W_dt, b_dt, deltab);

    // S: scan -> zb
    scan2_k<<<dim3(4096), blk, 0, stream>>>(
        deltab, ubuf, projb, A_log, Dv, resb, zb);

    // G5: out = zb @ WT_out^T
    mfma_k<2><<<dim3(16, 16), blk, 0, stream>>>(
        zb, 2048, WT_out, 2048, out, 1024, nullptr, nullptr, nullptr, 64);
}

// Round 4
// 524.665 us; speedup vs baseline: 4.5376x; 1.1241x over previous
//
#include <hip/hip_runtime.h>
#include <math.h>

// L=1024 B=2 F=1024 E=2 H=2048 N=16 R=64 K=4, M=2048 rows (m = l*2+b).
// Key layout decision this round: everything the scan touches is [h][m]
// (transposed), because the MFMA C-fragment holds 4 consecutive m per lane ->
// C^T stores are contiguous ushort4/float4. Scan then reads rows, not columns.
//   T : WT_in, WT_conv, WT_out, WT_ssm, WT_dt (bf16 [n][k]); xb = bf16(x)
//   G1: h = xb @ WT_in^T -> xs(bf16 [m][ch]) | resT(bf16 [h][m])
//   C : conv gather-GEMM -> u_mh(bf16 [m][h]) + uT(bf16 [h][m]), +bias, silu
//   G3: proj = u @ W_ssm, split-K=4, fp32 atomics, ld 128
//   G4: deltaT = clip(softplus(dtraw @ W_dt + b_dt))^T  (MFMA, fp32 [h][m])
//   S : chunked scan (16x64) reading rows -> zT (bf16 [h][m])
//   G5: out = z @ W_out with A transpose-staged from zT (fp32 out)

typedef unsigned short u16;
typedef unsigned int u32;
typedef __attribute__((ext_vector_type(8))) short short8;
typedef __attribute__((ext_vector_type(4))) float floatx4;
typedef __attribute__((ext_vector_type(4))) u16 ushort4v;

__device__ __forceinline__ u16 f2bf(float f) {
    u32 u = __float_as_uint(f);
    return (u16)((u + 0x7fffu + ((u >> 16) & 1u)) >> 16);
}
__device__ __forceinline__ float bf2f(u16 v) {
    return __uint_as_float((u32)v << 16);
}

#define APAD 40

// ---------------- generic fp32 -> bf16 transpose:  S[R][C] -> D[C][R] ----------------
__global__ __launch_bounds__(256) void trans_k(const float* __restrict__ S,
                                               u16* __restrict__ D, int R, int C)
{
    __shared__ u16 t[64][65];
    int br = blockIdx.x * 64;
    int bc = blockIdx.y * 64;
    int c = threadIdx.x & 63;
    int r0 = threadIdx.x >> 6;
#pragma unroll
    for (int i = 0; i < 16; ++i) {
        int r = r0 + i * 4;
        float v = 0.f;
        if (br + r < R && bc + c < C) v = S[(size_t)(br + r) * C + bc + c];
        t[r][c] = f2bf(v);
    }
    __syncthreads();
#pragma unroll
    for (int i = 0; i < 16; ++i) {
        int r = r0 + i * 4;
        if (bc + r < C && br + c < R)
            D[(size_t)(bc + r) * R + br + c] = t[c][r];
    }
}

// ---------------- x fp32 -> bf16 ----------------
__global__ __launch_bounds__(256) void cvt_k(const float* __restrict__ S, u16* __restrict__ D)
{
    int i = (blockIdx.x * 256 + threadIdx.x) * 4;
    float4 v = *(const float4*)(S + i);
    u16 o[4] = {f2bf(v.x), f2bf(v.y), f2bf(v.z), f2bf(v.w)};
    *(ulong1*)(D + i) = *(ulong1*)o;
}

// ---------------- proj dt-columns fp32 -> bf16 [2048][64] ----------------
__global__ __launch_bounds__(256) void cvtdt_k(const float* __restrict__ proj,
                                               u16* __restrict__ pb)
{
    int g = blockIdx.x * 256 + threadIdx.x;   // 32768 threads
    int m = g >> 4, i = (g & 15) * 4;
    float4 v = *(const float4*)(proj + (size_t)m * 128 + 32 + i);
    u16 o[4] = {f2bf(v.x), f2bf(v.y), f2bf(v.z), f2bf(v.w)};
    *(ulong1*)(pb + (size_t)m * 64 + i) = *(ulong1*)o;
}

// ---------------- bf16 MFMA GEMM: A[M][K] x B[N][K]^T, tile 128x64 ----------------
// MODE 0: G1 split xs[m][h] / resT[h][m]
// MODE 1: conv gather, +bias+silu -> u_mh[m][h] + uT[h][m]
// MODE 2: plain fp32 [m][n] out
// MODE 3: bias+softplus+clip -> fp32 transposed [n][m] (deltaT)
// TRANSA: A is stored [K][M] (k-major), stage with on-the-fly transpose.
template<int MODE, int TRANSA>
__global__ __launch_bounds__(256) void mfma_k(
    const u16* __restrict__ A, int lda,
    const u16* __restrict__ B, int ldb,
    float* __restrict__ Cf, int ldc,
    u16* __restrict__ Cb0, u16* __restrict__ Cb1,
    const float* __restrict__ bias, int nkt)
{
    __shared__ u16 As[128 * APAD];
    __shared__ u16 Bs[64 * APAD];
    const int tid = threadIdx.x;
    const int bm = blockIdx.y * 128;
    const int bn = blockIdx.x * 64;
    const int gofs = (MODE == 1 && bn >= 1024) ? 1024 : 0;
    const int lane = tid & 63, wave = tid >> 6, wm = wave * 32;
    const int m16 = lane & 15, q = lane >> 4;
    floatx4 acc[2][4] = {};
    const int ar = tid >> 2, ac = (tid & 3) * 8;

    for (int kt = 0; kt < nkt; ++kt) {
        const int k0 = kt * 32;
        if (TRANSA) {
            // A[K][M]: read short8 along m, scatter-transpose into As[m][k]
            const int kk = tid & 31;
            const int mg = tid >> 5;      // 0..7
#pragma unroll
            for (int p = 0; p < 2; ++p) {
                int mm = mg * 8 + p * 64;
                short8 v = *(const short8*)(A + (size_t)(k0 + kk) * lda + bm + mm);
#pragma unroll
                for (int i = 0; i < 8; ++i)
                    As[(mm + i) * APAD + kk] = (u16)v[i];
            }
        } else {
#pragma unroll
            for (int p = 0; p < 2; ++p) {
                int r = ar + p * 64;
                short8 v = {};
                if (MODE == 1) {
                    int tap = k0 >> 10, ck = k0 & 1023;
                    int rg = bm + r + 2 * tap - 6;   // causal shift, tile-uniform
                    if (rg >= 0)
                        v = *(const short8*)(A + (size_t)rg * lda + gofs + ck + ac);
                } else {
                    v = *(const short8*)(A + (size_t)(bm + r) * lda + k0 + ac);
                }
                *(short8*)(As + r * APAD + ac) = v;
            }
        }
        *(short8*)(Bs + ar * APAD + ac) =
            *(const short8*)(B + (size_t)(bn + ar) * ldb + k0 + ac);
        __syncthreads();

        short8 af[2], bfr[4];
#pragma unroll
        for (int ti = 0; ti < 2; ++ti)
            af[ti] = *(const short8*)(As + (wm + ti * 16 + m16) * APAD + q * 8);
#pragma unroll
        for (int tj = 0; tj < 4; ++tj)
            bfr[tj] = *(const short8*)(Bs + (tj * 16 + m16) * APAD + q * 8);
#pragma unroll
        for (int ti = 0; ti < 2; ++ti)
#pragma unroll
            for (int tj = 0; tj < 4; ++tj)
                acc[ti][tj] = __builtin_amdgcn_mfma_f32_16x16x32_bf16(
                    af[ti], bfr[tj], acc[ti][tj], 0, 0, 0);
        __syncthreads();
    }

#pragma unroll
    for (int tj = 0; tj < 4; ++tj) {
        int gn = bn + tj * 16 + m16;
        float bv = (MODE == 1 || MODE == 3) ? bias[gn] : 0.f;
#pragma unroll
        for (int ti = 0; ti < 2; ++ti) {
            int gm0 = bm + wm + ti * 16 + q * 4;
            if (MODE == 0) {
                if (gn < 2048) {
#pragma unroll
                    for (int r = 0; r < 4; ++r)
                        Cb0[(size_t)(gm0 + r) * 2048 + gn] = f2bf(acc[ti][tj][r]);
                } else {
                    ushort4v h;
#pragma unroll
                    for (int r = 0; r < 4; ++r) h[r] = f2bf(acc[ti][tj][r]);
                    *(ushort4v*)(Cb1 + (size_t)(gn - 2048) * 2048 + gm0) = h;
                }
            } else if (MODE == 1) {
                ushort4v h;
#pragma unroll
                for (int r = 0; r < 4; ++r) {
                    float v = acc[ti][tj][r] + bv;
                    v = v / (1.f + __expf(-v));
                    u16 hv = f2bf(v);
                    h[r] = hv;
                    Cb0[(size_t)(gm0 + r) * 2048 + gn] = hv;   // u_mh
                }
                *(ushort4v*)(Cb1 + (size_t)gn * 2048 + gm0) = h;  // uT
            } else if (MODE == 2) {
#pragma unroll
                for (int r = 0; r < 4; ++r)
                    Cf[(size_t)(gm0 + r) * ldc + gn] = acc[ti][tj][r];
            } else {  // MODE 3: softplus+clip, transposed float4
                float t[4];
#pragma unroll
                for (int r = 0; r < 4; ++r) {
                    float v = acc[ti][tj][r] + bv;
                    v = (v > 15.f) ? v : log1pf(__expf(v));
                    t[r] = fminf(fmaxf(v, 0.001f), 0.1f);
                }
                *(float4*)(Cf + (size_t)gn * ldc + gm0) =
                    make_float4(t[0], t[1], t[2], t[3]);
            }
        }
    }
}

// ---------------- G3: proj = u @ W_ssm, split-K MFMA with fp32 atomics ----------------
__global__ __launch_bounds__(256) void g3_k(
    const u16* __restrict__ A,      // u_mh bf16 [2048][2048]
    const u16* __restrict__ Bw,     // WT_ssm bf16 [128][2048]
    float* __restrict__ proj)       // [2048][128] fp32, pre-zeroed
{
    __shared__ u16 As[128 * APAD];
    __shared__ u16 Bs[64 * APAD];
    const int tid = threadIdx.x;
    const int bn = blockIdx.x * 64;
    const int bm = blockIdx.y * 128;
    const int kb = blockIdx.z * 512;
    const int lane = tid & 63, wave = tid >> 6, wm = wave * 32;
    const int m16 = lane & 15, q = lane >> 4;
    floatx4 acc[2][4] = {};
    const int ar = tid >> 2, ac = (tid & 3) * 8;

    for (int kt = 0; kt < 16; ++kt) {
        const int k0 = kb + kt * 32;
#pragma unroll
        for (int p = 0; p < 2; ++p) {
            int r = ar + p * 64;
            *(short8*)(As + r * APAD + ac) =
                *(const short8*)(A + (size_t)(bm + r) * 2048 + k0 + ac);
        }
        *(short8*)(Bs + ar * APAD + ac) =
            *(const short8*)(Bw + (size_t)(bn + ar) * 2048 + k0 + ac);
        __syncthreads();

        short8 af[2], bfr[4];
#pragma unroll
        for (int ti = 0; ti < 2; ++ti)
            af[ti] = *(const short8*)(As + (wm + ti * 16 + m16) * APAD + q * 8);
#pragma unroll
        for (int tj = 0; tj < 4; ++tj)
            bfr[tj] = *(const short8*)(Bs + (tj * 16 + m16) * APAD + q * 8);
#pragma unroll
        for (int ti = 0; ti < 2; ++ti)
#pragma unroll
            for (int tj = 0; tj < 4; ++tj)
                acc[ti][tj] = __builtin_amdgcn_mfma_f32_16x16x32_bf16(
                    af[ti], bfr[tj], acc[ti][tj], 0, 0, 0);
        __syncthreads();
    }

#pragma unroll
    for (int tj = 0; tj < 4; ++tj) {
        int gn = bn + tj * 16 + m16;
#pragma unroll
        for (int ti = 0; ti < 2; ++ti)
#pragma unroll
            for (int r = 0; r < 4; ++r) {
                int gm = bm + wm + ti * 16 + q * 4 + r;
                atomicAdd(proj + (size_t)gm * 128 + gn, acc[ti][tj][r]);
            }
    }
}

// ---------------- chunked selective scan, row-major operands ----------------
__global__ __launch_bounds__(256) void scan3_k(
    const float* __restrict__ deltaT,  // [2048 h][2048 m]
    const u16* __restrict__ uT,        // [2048 h][2048 m] bf16
    const float* __restrict__ proj,    // [2048 m][128] (B|C|dtraw|pad)
    const float* __restrict__ A_log,
    const float* __restrict__ Dvec,
    const u16* __restrict__ resT,      // [2048 h][2048 m] bf16
    u16* __restrict__ zT)              // [2048 h][2048 m] bf16
{
    __shared__ float lP[16][16], lS[16][16], lI[16][16];
    const int h = blockIdx.x & 2047;
    const int b = blockIdx.x >> 11;
    const int tid = threadIdx.x;
    const int n = tid & 15;
    const int c = tid >> 4;
    const int l0 = c * 64;

    const float Ahn = -__expf(A_log[h * 16 + n]);
    const float* drow = deltaT + (size_t)h * 2048;
    const u16*   urow = uT     + (size_t)h * 2048;

    float s = 0.f, P = 1.f;
    for (int j = 0; j < 64; ++j) {
        int m = (l0 + j) * 2 + b;
        float dt = drow[m];
        float uu = bf2f(urow[m]);
        float Bm = proj[(size_t)m * 128 + n];
        float dA = __expf(dt * Ahn);
        s = fmaf(dA, s, dt * uu * Bm);
        P *= dA;
    }
    lP[c][n] = P;
    lS[c][n] = s;
    __syncthreads();
    if (tid < 16) {
        float X = 0.f;
#pragma unroll
        for (int cc = 0; cc < 16; ++cc) {
            lI[cc][tid] = X;
            X = fmaf(lP[cc][tid], X, lS[cc][tid]);
        }
    }
    __syncthreads();

    s = lI[c][n];
    const float Dh = Dvec[h];
    for (int j = 0; j < 64; ++j) {
        int m = (l0 + j) * 2 + b;
        float dt = drow[m];
        float uu = bf2f(urow[m]);
        float Bm = proj[(size_t)m * 128 + n];
        float Cm = proj[(size_t)m * 128 + 16 + n];
        float dA = __expf(dt * Ahn);
        s = fmaf(dA, s, dt * uu * Bm);
        float val = Cm * s;
        val += __shfl_xor(val, 1, 16);
        val += __shfl_xor(val, 2, 16);
        val += __shfl_xor(val, 4, 16);
        val += __shfl_xor(val, 8, 16);
        if (n == 0) {
            float y = val + uu * Dh;
            float r = bf2f(resT[(size_t)h * 2048 + m]);
            zT[(size_t)h * 2048 + m] = f2bf(y * (r / (1.f + __expf(-r))));
        }
    }
}

extern "C" void kernel_launch(void* const* d_in, const int* in_sizes, int n_in,
                              void* d_out, int out_size, void* d_ws, size_t ws_size,
                              hipStream_t stream)
{
    const float* x      = (const float*)d_in[0];
    const float* W_in   = (const float*)d_in[1];
    const float* W_conv = (const float*)d_in[2];
    const float* b_conv = (const float*)d_in[3];
    const float* A_log  = (const float*)d_in[4];
    const float* Dv     = (const float*)d_in[5];
    const float* W_ssm  = (const float*)d_in[6];
    const float* W_dt   = (const float*)d_in[7];
    const float* b_dt   = (const float*)d_in[8];
    const float* W_out  = (const float*)d_in[9];
    float* out = (float*)d_out;

    // ws layout (~57 MB), lifetime-aliased:
    //  off  0M: xb bf16 [2048][1024] (..G1) -> proj fp32 [2048][128] + pb_dt@2M (G3..)
    //  off  4M: WT_in bf16 [4096][1024] (..G1) -> u_mh bf16 [2048][2048] (conv..G3)
    //  off 12M: xsbf bf16 [2048][2048] (G1..conv) -> zT bf16 [h][m] (scan..G5)
    //  off 20M: resT bf16 [2048 h][2048 m] (G1..scan)
    //  off 28M: WT_cv bf16 [2048][4096] (..conv) -> deltaT fp32 [h][m] (G4..scan)
    //  off 44M: uT bf16 [2048 h][2048 m] (conv..scan)
    //  off 52M: WT_out bf16 [1024][2048] (..G5)
    //  off 56M: WT_ssm bf16 [128][2048] (..G3)
    //  off 56.5M: WT_dt bf16 [2048][64] (..G4)
    char* wsc = (char*)d_ws;
    u16*   xb     = (u16*)wsc;
    float* projb  = (float*)wsc;
    u16*   pb_dt  = (u16*)(wsc + (2u << 20));
    u16*   WT_in  = (u16*)(wsc + (4u << 20));
    u16*   u_mh   = (u16*)(wsc + (4u << 20));
    u16*   xsbf   = (u16*)(wsc + (12u << 20));
    u16*   zT     = xsbf;
    u16*   resT   = (u16*)(wsc + (20u << 20));
    u16*   WT_cv  = (u16*)(wsc + (28u << 20));
    float* deltaT = (float*)(wsc + (28u << 20));
    u16*   uT     = (u16*)(wsc + (44u << 20));
    u16*   WT_out = (u16*)(wsc + (52u << 20));
    u16*   WT_ssm = (u16*)(wsc + (56u << 20));
    u16*   WT_dt  = (u16*)(wsc + (56u << 20) + (512u << 10));

    dim3 blk(256);

    // T: transposes + converts
    trans_k<<<dim3(64, 32), blk, 0, stream>>>(W_conv, WT_cv, 4096, 2048);
    trans_k<<<dim3(16, 64), blk, 0, stream>>>(W_in, WT_in, 1024, 4096);
    trans_k<<<dim3(32, 16), blk, 0, stream>>>(W_out, WT_out, 2048, 1024);
    trans_k<<<dim3(32, 2),  blk, 0, stream>>>(W_ssm, WT_ssm, 2048, 96);
    trans_k<<<dim3(1, 32),  blk, 0, stream>>>(W_dt, WT_dt, 64, 2048);
    cvt_k<<<dim3(2048), blk, 0, stream>>>(x, xb);

    // G1: xs[m][ch] | resT[h][m]
    mfma_k<0, 0><<<dim3(64, 16), blk, 0, stream>>>(
        xb, 1024, WT_in, 1024, nullptr, 0, xsbf, resT, nullptr, 32);

    // C: conv -> u_mh + uT
    mfma_k<1, 0><<<dim3(32, 16), blk, 0, stream>>>(
        xsbf, 2048, WT_cv, 4096, nullptr, 0, u_mh, uT, b_conv, 128);

    // G3: proj (split-K atomics)
    hipMemsetAsync(projb, 0, 2048 * 128 * sizeof(float), stream);
    g3_k<<<dim3(2, 16, 4), blk, 0, stream>>>(u_mh, WT_ssm, projb);

    // dt columns -> bf16
    cvtdt_k<<<dim3(128), blk, 0, stream>>>(projb, pb_dt);

    // G4: deltaT = clip(softplus(dtraw @ W_dt + b_dt))^T
    mfma_k<3, 0><<<dim3(32, 16), blk, 0, stream>>>(
        pb_dt, 64, WT_dt, 64, deltaT, 2048, nullptr, nullptr, b_dt, 2);

    // S: scan -> zT
    scan3_k<<<dim3(4096), blk, 0, stream>>>(
        deltaT, uT, projb, A_log, Dv, resT, zT);

    // G5: out = z @ W_out (A transpose-staged from zT)
    mfma_k<2, 1><<<dim3(16, 16), blk, 0, stream>>>(
        zT, 2048, WT_out, 2048, out, 1024, nullptr, nullptr, nullptr, 64);
}

// Round 5
// 476.680 us; speedup vs baseline: 4.9944x; 1.1007x over previous
//
#include <hip/hip_runtime.h>
#include <math.h>

// L=1024 B=2 F=1024 E=2 H=2048 N=16 R=64 K=4, M=2048 rows (m = l*2+b).
// Scan-facing tensors are [h][m] (transposed): MFMA C-fragments hold 4
// consecutive m per lane -> C^T stores are contiguous. Round-4 change: scan
// block covers one h with BOTH batches per lane (float2/u32 paired loads,
// m=2l+b adjacency), LDS yrow + vectorized coalesced zT row writes.
//   T : WT_in, WT_conv, WT_out, WT_ssm, WT_dt (bf16 [n][k]); xb = bf16(x)
//   G1: h = xb @ WT_in^T -> xs(bf16 [m][ch]) | resT(bf16 [h][m])
//   C : conv gather-GEMM -> u_mh(bf16 [m][h]) + uT(bf16 [h][m]), +bias, silu
//   G3: proj = u @ W_ssm, split-K=4, fp32 atomics, ld 128
//   G4: deltaT = clip(softplus(dtraw @ W_dt + b_dt))^T  (MFMA, fp32 [h][m])
//   S : scan, 1 block/h, 32 chunks x 32 steps, 2 states/lane -> zT bf16 [h][m]
//   G5: out = z @ W_out with A transpose-staged from zT (fp32 out)

typedef unsigned short u16;
typedef unsigned int u32;
typedef __attribute__((ext_vector_type(8))) short short8;
typedef __attribute__((ext_vector_type(4))) float floatx4;
typedef __attribute__((ext_vector_type(4))) u16 ushort4v;

__device__ __forceinline__ u16 f2bf(float f) {
    u32 u = __float_as_uint(f);
    return (u16)((u + 0x7fffu + ((u >> 16) & 1u)) >> 16);
}
__device__ __forceinline__ float bf2f(u16 v) {
    return __uint_as_float((u32)v << 16);
}

#define APAD 40

// ---------------- generic fp32 -> bf16 transpose:  S[R][C] -> D[C][R] ----------------
__global__ __launch_bounds__(256) void trans_k(const float* __restrict__ S,
                                               u16* __restrict__ D, int R, int C)
{
    __shared__ u16 t[64][65];
    int br = blockIdx.x * 64;
    int bc = blockIdx.y * 64;
    int c = threadIdx.x & 63;
    int r0 = threadIdx.x >> 6;
#pragma unroll
    for (int i = 0; i < 16; ++i) {
        int r = r0 + i * 4;
        float v = 0.f;
        if (br + r < R && bc + c < C) v = S[(size_t)(br + r) * C + bc + c];
        t[r][c] = f2bf(v);
    }
    __syncthreads();
#pragma unroll
    for (int i = 0; i < 16; ++i) {
        int r = r0 + i * 4;
        if (bc + r < C && br + c < R)
            D[(size_t)(bc + r) * R + br + c] = t[c][r];
    }
}

// ---------------- x fp32 -> bf16 ----------------
__global__ __launch_bounds__(256) void cvt_k(const float* __restrict__ S, u16* __restrict__ D)
{
    int i = (blockIdx.x * 256 + threadIdx.x) * 4;
    float4 v = *(const float4*)(S + i);
    u16 o[4] = {f2bf(v.x), f2bf(v.y), f2bf(v.z), f2bf(v.w)};
    *(ulong1*)(D + i) = *(ulong1*)o;
}

// ---------------- proj dt-columns fp32 -> bf16 [2048][64] ----------------
__global__ __launch_bounds__(256) void cvtdt_k(const float* __restrict__ proj,
                                               u16* __restrict__ pb)
{
    int g = blockIdx.x * 256 + threadIdx.x;   // 32768 threads
    int m = g >> 4, i = (g & 15) * 4;
    float4 v = *(const float4*)(proj + (size_t)m * 128 + 32 + i);
    u16 o[4] = {f2bf(v.x), f2bf(v.y), f2bf(v.z), f2bf(v.w)};
    *(ulong1*)(pb + (size_t)m * 64 + i) = *(ulong1*)o;
}

// ---------------- bf16 MFMA GEMM: A[M][K] x B[N][K]^T, tile 128x64 ----------------
// MODE 0: G1 split xs[m][h] / resT[h][m]
// MODE 1: conv gather, +bias+silu -> u_mh[m][h] + uT[h][m]
// MODE 2: plain fp32 [m][n] out
// MODE 3: bias+softplus+clip -> fp32 transposed [n][m] (deltaT)
// TRANSA: A is stored [K][M] (k-major), stage with on-the-fly transpose.
template<int MODE, int TRANSA>
__global__ __launch_bounds__(256) void mfma_k(
    const u16* __restrict__ A, int lda,
    const u16* __restrict__ B, int ldb,
    float* __restrict__ Cf, int ldc,
    u16* __restrict__ Cb0, u16* __restrict__ Cb1,
    const float* __restrict__ bias, int nkt)
{
    __shared__ u16 As[128 * APAD];
    __shared__ u16 Bs[64 * APAD];
    const int tid = threadIdx.x;
    const int bm = blockIdx.y * 128;
    const int bn = blockIdx.x * 64;
    const int gofs = (MODE == 1 && bn >= 1024) ? 1024 : 0;
    const int lane = tid & 63, wave = tid >> 6, wm = wave * 32;
    const int m16 = lane & 15, q = lane >> 4;
    floatx4 acc[2][4] = {};
    const int ar = tid >> 2, ac = (tid & 3) * 8;

    for (int kt = 0; kt < nkt; ++kt) {
        const int k0 = kt * 32;
        if (TRANSA) {
            const int kk = tid & 31;
            const int mg = tid >> 5;
#pragma unroll
            for (int p = 0; p < 2; ++p) {
                int mm = mg * 8 + p * 64;
                short8 v = *(const short8*)(A + (size_t)(k0 + kk) * lda + bm + mm);
#pragma unroll
                for (int i = 0; i < 8; ++i)
                    As[(mm + i) * APAD + kk] = (u16)v[i];
            }
        } else {
#pragma unroll
            for (int p = 0; p < 2; ++p) {
                int r = ar + p * 64;
                short8 v = {};
                if (MODE == 1) {
                    int tap = k0 >> 10, ck = k0 & 1023;
                    int rg = bm + r + 2 * tap - 6;   // causal shift, tile-uniform
                    if (rg >= 0)
                        v = *(const short8*)(A + (size_t)rg * lda + gofs + ck + ac);
                } else {
                    v = *(const short8*)(A + (size_t)(bm + r) * lda + k0 + ac);
                }
                *(short8*)(As + r * APAD + ac) = v;
            }
        }
        *(short8*)(Bs + ar * APAD + ac) =
            *(const short8*)(B + (size_t)(bn + ar) * ldb + k0 + ac);
        __syncthreads();

        short8 af[2], bfr[4];
#pragma unroll
        for (int ti = 0; ti < 2; ++ti)
            af[ti] = *(const short8*)(As + (wm + ti * 16 + m16) * APAD + q * 8);
#pragma unroll
        for (int tj = 0; tj < 4; ++tj)
            bfr[tj] = *(const short8*)(Bs + (tj * 16 + m16) * APAD + q * 8);
#pragma unroll
        for (int ti = 0; ti < 2; ++ti)
#pragma unroll
            for (int tj = 0; tj < 4; ++tj)
                acc[ti][tj] = __builtin_amdgcn_mfma_f32_16x16x32_bf16(
                    af[ti], bfr[tj], acc[ti][tj], 0, 0, 0);
        __syncthreads();
    }

#pragma unroll
    for (int tj = 0; tj < 4; ++tj) {
        int gn = bn + tj * 16 + m16;
        float bv = (MODE == 1 || MODE == 3) ? bias[gn] : 0.f;
#pragma unroll
        for (int ti = 0; ti < 2; ++ti) {
            int gm0 = bm + wm + ti * 16 + q * 4;
            if (MODE == 0) {
                if (gn < 2048) {
#pragma unroll
                    for (int r = 0; r < 4; ++r)
                        Cb0[(size_t)(gm0 + r) * 2048 + gn] = f2bf(acc[ti][tj][r]);
                } else {
                    ushort4v h;
#pragma unroll
                    for (int r = 0; r < 4; ++r) h[r] = f2bf(acc[ti][tj][r]);
                    *(ushort4v*)(Cb1 + (size_t)(gn - 2048) * 2048 + gm0) = h;
                }
            } else if (MODE == 1) {
                ushort4v h;
#pragma unroll
                for (int r = 0; r < 4; ++r) {
                    float v = acc[ti][tj][r] + bv;
                    v = v / (1.f + __expf(-v));
                    u16 hv = f2bf(v);
                    h[r] = hv;
                    Cb0[(size_t)(gm0 + r) * 2048 + gn] = hv;   // u_mh
                }
                *(ushort4v*)(Cb1 + (size_t)gn * 2048 + gm0) = h;  // uT
            } else if (MODE == 2) {
#pragma unroll
                for (int r = 0; r < 4; ++r)
                    Cf[(size_t)(gm0 + r) * ldc + gn] = acc[ti][tj][r];
            } else {  // MODE 3: softplus+clip, transposed float4
                float t[4];
#pragma unroll
                for (int r = 0; r < 4; ++r) {
                    float v = acc[ti][tj][r] + bv;
                    v = (v > 15.f) ? v : log1pf(__expf(v));
                    t[r] = fminf(fmaxf(v, 0.001f), 0.1f);
                }
                *(float4*)(Cf + (size_t)gn * ldc + gm0) =
                    make_float4(t[0], t[1], t[2], t[3]);
            }
        }
    }
}

// ---------------- G3: proj = u @ W_ssm, split-K MFMA with fp32 atomics ----------------
__global__ __launch_bounds__(256) void g3_k(
    const u16* __restrict__ A,      // u_mh bf16 [2048][2048]
    const u16* __restrict__ Bw,     // WT_ssm bf16 [128][2048]
    float* __restrict__ proj)       // [2048][128] fp32, pre-zeroed
{
    __shared__ u16 As[128 * APAD];
    __shared__ u16 Bs[64 * APAD];
    const int tid = threadIdx.x;
    const int bn = blockIdx.x * 64;
    const int bm = blockIdx.y * 128;
    const int kb = blockIdx.z * 512;
    const int lane = tid & 63, wave = tid >> 6, wm = wave * 32;
    const int m16 = lane & 15, q = lane >> 4;
    floatx4 acc[2][4] = {};
    const int ar = tid >> 2, ac = (tid & 3) * 8;

    for (int kt = 0; kt < 16; ++kt) {
        const int k0 = kb + kt * 32;
#pragma unroll
        for (int p = 0; p < 2; ++p) {
            int r = ar + p * 64;
            *(short8*)(As + r * APAD + ac) =
                *(const short8*)(A + (size_t)(bm + r) * 2048 + k0 + ac);
        }
        *(short8*)(Bs + ar * APAD + ac) =
            *(const short8*)(Bw + (size_t)(bn + ar) * 2048 + k0 + ac);
        __syncthreads();

        short8 af[2], bfr[4];
#pragma unroll
        for (int ti = 0; ti < 2; ++ti)
            af[ti] = *(const short8*)(As + (wm + ti * 16 + m16) * APAD + q * 8);
#pragma unroll
        for (int tj = 0; tj < 4; ++tj)
            bfr[tj] = *(const short8*)(Bs + (tj * 16 + m16) * APAD + q * 8);
#pragma unroll
        for (int ti = 0; ti < 2; ++ti)
#pragma unroll
            for (int tj = 0; tj < 4; ++tj)
                acc[ti][tj] = __builtin_amdgcn_mfma_f32_16x16x32_bf16(
                    af[ti], bfr[tj], acc[ti][tj], 0, 0, 0);
        __syncthreads();
    }

#pragma unroll
    for (int tj = 0; tj < 4; ++tj) {
        int gn = bn + tj * 16 + m16;
#pragma unroll
        for (int ti = 0; ti < 2; ++ti)
#pragma unroll
            for (int r = 0; r < 4; ++r) {
                int gm = bm + wm + ti * 16 + q * 4 + r;
                atomicAdd(proj + (size_t)gm * 128 + gn, acc[ti][tj][r]);
            }
    }
}

// ---------------- scan: 1 block per h, both batches per lane ----------------
// tid = c*16+n (c: 32 chunks of 32 tokens). Lane carries s/P for b=0 and b=1.
__global__ __launch_bounds__(512) void scan4_k(
    const float* __restrict__ deltaT,  // [2048 h][2048 m]
    const u16* __restrict__ uT,        // [2048 h][2048 m] bf16
    const float* __restrict__ proj,    // [2048 m][128] (B|C|dtraw|pad)
    const float* __restrict__ A_log,
    const float* __restrict__ Dvec,
    const u16* __restrict__ resT,      // [2048 h][2048 m] bf16
    u16* __restrict__ zT)              // [2048 h][2048 m] bf16
{
    __shared__ float lP[2][32][16], lS[2][32][16], lI[2][32][16];
    __shared__ float yrow[2048];
    const int h = blockIdx.x;
    const int tid = threadIdx.x;
    const int n = tid & 15;
    const int c = tid >> 4;        // 0..31
    const int l0 = c * 32;

    const float Ahn = -__expf(A_log[h * 16 + n]);
    const float* drow = deltaT + (size_t)h * 2048;
    const u16*   urow = uT     + (size_t)h * 2048;

    float s0 = 0.f, P0 = 1.f, s1 = 0.f, P1 = 1.f;
    for (int j = 0; j < 32; ++j) {
        int l = l0 + j;
        float2 dtv = *(const float2*)(drow + 2 * l);
        u32 uv = *(const u32*)(urow + 2 * l);
        float uu0 = __uint_as_float(uv << 16);
        float uu1 = __uint_as_float(uv & 0xffff0000u);
        float B0 = proj[(size_t)(2 * l) * 128 + n];
        float B1 = proj[(size_t)(2 * l + 1) * 128 + n];
        float e0 = __expf(dtv.x * Ahn);
        float e1 = __expf(dtv.y * Ahn);
        s0 = fmaf(e0, s0, dtv.x * uu0 * B0);
        s1 = fmaf(e1, s1, dtv.y * uu1 * B1);
        P0 *= e0;
        P1 *= e1;
    }
    lP[0][c][n] = P0; lS[0][c][n] = s0;
    lP[1][c][n] = P1; lS[1][c][n] = s1;
    __syncthreads();
    if (tid < 32) {
        int bb = tid >> 4, nn = tid & 15;
        float X = 0.f;
#pragma unroll
        for (int cc = 0; cc < 32; ++cc) {
            lI[bb][cc][nn] = X;
            X = fmaf(lP[bb][cc][nn], X, lS[bb][cc][nn]);
        }
    }
    __syncthreads();

    s0 = lI[0][c][n];
    s1 = lI[1][c][n];
    const float Dh = Dvec[h];
    for (int j = 0; j < 32; ++j) {
        int l = l0 + j;
        float2 dtv = *(const float2*)(drow + 2 * l);
        u32 uv = *(const u32*)(urow + 2 * l);
        float uu0 = __uint_as_float(uv << 16);
        float uu1 = __uint_as_float(uv & 0xffff0000u);
        float B0 = proj[(size_t)(2 * l) * 128 + n];
        float B1 = proj[(size_t)(2 * l + 1) * 128 + n];
        float C0 = proj[(size_t)(2 * l) * 128 + 16 + n];
        float C1 = proj[(size_t)(2 * l + 1) * 128 + 16 + n];
        float e0 = __expf(dtv.x * Ahn);
        float e1 = __expf(dtv.y * Ahn);
        s0 = fmaf(e0, s0, dtv.x * uu0 * B0);
        s1 = fmaf(e1, s1, dtv.y * uu1 * B1);
        float v0 = C0 * s0;
        float v1 = C1 * s1;
        v0 += __shfl_xor(v0, 1, 16);
        v0 += __shfl_xor(v0, 2, 16);
        v0 += __shfl_xor(v0, 4, 16);
        v0 += __shfl_xor(v0, 8, 16);
        v1 += __shfl_xor(v1, 1, 16);
        v1 += __shfl_xor(v1, 2, 16);
        v1 += __shfl_xor(v1, 4, 16);
        v1 += __shfl_xor(v1, 8, 16);
        if (n == 0) {
            yrow[2 * l]     = v0 + uu0 * Dh;
            yrow[2 * l + 1] = v1 + uu1 * Dh;
        }
    }
    __syncthreads();

    // vectorized epilogue: z = y * silu(res), coalesced full-row write
    {
        int t0 = tid * 4;
        ushort4v rv = *(const ushort4v*)(resT + (size_t)h * 2048 + t0);
        u16 o[4];
#pragma unroll
        for (int i = 0; i < 4; ++i) {
            float r = bf2f(rv[i]);
            float y = yrow[t0 + i];
            o[i] = f2bf(y * (r / (1.f + __expf(-r))));
        }
        *(ulong1*)(zT + (size_t)h * 2048 + t0) = *(ulong1*)o;
    }
}

extern "C" void kernel_launch(void* const* d_in, const int* in_sizes, int n_in,
                              void* d_out, int out_size, void* d_ws, size_t ws_size,
                              hipStream_t stream)
{
    const float* x      = (const float*)d_in[0];
    const float* W_in   = (const float*)d_in[1];
    const float* W_conv = (const float*)d_in[2];
    const float* b_conv = (const float*)d_in[3];
    const float* A_log  = (const float*)d_in[4];
    const float* Dv     = (const float*)d_in[5];
    const float* W_ssm  = (const float*)d_in[6];
    const float* W_dt   = (const float*)d_in[7];
    const float* b_dt   = (const float*)d_in[8];
    const float* W_out  = (const float*)d_in[9];
    float* out = (float*)d_out;

    // ws layout (~57 MB), lifetime-aliased (same as round 3):
    char* wsc = (char*)d_ws;
    u16*   xb     = (u16*)wsc;
    float* projb  = (float*)wsc;
    u16*   pb_dt  = (u16*)(wsc + (2u << 20));
    u16*   WT_in  = (u16*)(wsc + (4u << 20));
    u16*   u_mh   = (u16*)(wsc + (4u << 20));
    u16*   xsbf   = (u16*)(wsc + (12u << 20));
    u16*   zT     = xsbf;
    u16*   resT   = (u16*)(wsc + (20u << 20));
    u16*   WT_cv  = (u16*)(wsc + (28u << 20));
    float* deltaT = (float*)(wsc + (28u << 20));
    u16*   uT     = (u16*)(wsc + (44u << 20));
    u16*   WT_out = (u16*)(wsc + (52u << 20));
    u16*   WT_ssm = (u16*)(wsc + (56u << 20));
    u16*   WT_dt  = (u16*)(wsc + (56u << 20) + (512u << 10));

    dim3 blk(256);

    // T: transposes + converts
    trans_k<<<dim3(64, 32), blk, 0, stream>>>(W_conv, WT_cv, 4096, 2048);
    trans_k<<<dim3(16, 64), blk, 0, stream>>>(W_in, WT_in, 1024, 4096);
    trans_k<<<dim3(32, 16), blk, 0, stream>>>(W_out, WT_out, 2048, 1024);
    trans_k<<<dim3(32, 2),  blk, 0, stream>>>(W_ssm, WT_ssm, 2048, 96);
    trans_k<<<dim3(1, 32),  blk, 0, stream>>>(W_dt, WT_dt, 64, 2048);
    cvt_k<<<dim3(2048), blk, 0, stream>>>(x, xb);

    // G1: xs[m][ch] | resT[h][m]
    mfma_k<0, 0><<<dim3(64, 16), blk, 0, stream>>>(
        xb, 1024, WT_in, 1024, nullptr, 0, xsbf, resT, nullptr, 32);

    // C: conv -> u_mh + uT
    mfma_k<1, 0><<<dim3(32, 16), blk, 0, stream>>>(
        xsbf, 2048, WT_cv, 4096, nullptr, 0, u_mh, uT, b_conv, 128);

    // G3: proj (split-K atomics)
    hipMemsetAsync(projb, 0, 2048 * 128 * sizeof(float), stream);
    g3_k<<<dim3(2, 16, 4), blk, 0, stream>>>(u_mh, WT_ssm, projb);

    // dt columns -> bf16
    cvtdt_k<<<dim3(128), blk, 0, stream>>>(projb, pb_dt);

    // G4: deltaT = clip(softplus(dtraw @ W_dt + b_dt))^T
    mfma_k<3, 0><<<dim3(32, 16), blk, 0, stream>>>(
        pb_dt, 64, WT_dt, 64, deltaT, 2048, nullptr, nullptr, b_dt, 2);

    // S: scan -> zT (1 block/h, 512 threads)
    scan4_k<<<dim3(2048), dim3(512), 0, stream>>>(
        deltaT, uT, projb, A_log, Dv, resT, zT);

    // G5: out = z @ W_out (A transpose-staged from zT)
    mfma_k<2, 1><<<dim3(16, 16), blk, 0, stream>>>(
        zT, 2048, WT_out, 2048, out, 1024, nullptr, nullptr, nullptr, 64);
}

// Round 6
// 386.013 us; speedup vs baseline: 6.1675x; 1.2349x over previous
//
#include <hip/hip_runtime.h>
#include <math.h>

// L=1024 B=2 F=1024 E=2 H=2048 N=16 R=64 K=4, M=2048 rows (m = l*2+b).
// Round-6: m97-style GEMM core for G1/conv/G5 — global_load_lds width-16
// async staging, BK=64, unpadded LDS with XOR chunk swizzle (p = c ^ (r&7)),
// 128x64 tiles. Scan-facing tensors stay [h][m].
//   T : WT_in, WT_conv, WT_out, WT_ssm, WT_dt (bf16 [n][k]); xb = bf16(x)
//   G1: h = xb @ WT_in^T -> xs(bf16 [m][ch] via LDS repack) | resT(bf16 [h][m])
//   C : conv gather-GEMM -> u_mh(repack) + uT direct, +bias, silu
//   G3: proj = u @ W_ssm, split-K=4, fp32 atomics, ld 128
//   G4: deltaT = clip(softplus(dtraw @ W_dt + b_dt))^T  (old padded kernel)
//   S : scan, 1 block/h, 2 states/lane -> zT bf16 [h][m]
//   TZ: zT -> z_mh (bf16 transpose)
//   G5: out = z_mh @ WT_out^T (fp32)

typedef unsigned short u16;
typedef unsigned int u32;
typedef __attribute__((ext_vector_type(8))) short short8;
typedef __attribute__((ext_vector_type(4))) float floatx4;
typedef __attribute__((ext_vector_type(4))) u16 ushort4v;

__device__ __forceinline__ u16 f2bf(float f) {
    u32 u = __float_as_uint(f);
    return (u16)((u + 0x7fffu + ((u >> 16) & 1u)) >> 16);
}
__device__ __forceinline__ float bf2f(u16 v) {
    return __uint_as_float((u32)v << 16);
}

// async global->LDS, 16 bytes per lane (CK-style casts)
__device__ __forceinline__ void gl_lds16(const u16* g, u16* l) {
    auto gp = reinterpret_cast<const __attribute__((address_space(1))) u32*>(
        reinterpret_cast<uintptr_t>(g));
    auto lp = reinterpret_cast<__attribute__((address_space(3))) u32*>(
        reinterpret_cast<uintptr_t>(l));
    __builtin_amdgcn_global_load_lds(gp, lp, 16, 0, 0);
}

// ---------------- generic fp32 -> bf16 transpose:  S[R][C] -> D[C][R] ----------------
__global__ __launch_bounds__(256) void trans_k(const float* __restrict__ S,
                                               u16* __restrict__ D, int R, int C)
{
    __shared__ u16 t[64][65];
    int br = blockIdx.x * 64;
    int bc = blockIdx.y * 64;
    int c = threadIdx.x & 63;
    int r0 = threadIdx.x >> 6;
#pragma unroll
    for (int i = 0; i < 16; ++i) {
        int r = r0 + i * 4;
        float v = 0.f;
        if (br + r < R && bc + c < C) v = S[(size_t)(br + r) * C + bc + c];
        t[r][c] = f2bf(v);
    }
    __syncthreads();
#pragma unroll
    for (int i = 0; i < 16; ++i) {
        int r = r0 + i * 4;
        if (bc + r < C && br + c < R)
            D[(size_t)(bc + r) * R + br + c] = t[c][r];
    }
}

// ---------------- bf16 [2048][2048] transpose (zT -> z_mh) ----------------
__global__ __launch_bounds__(256) void tbf_k(const u16* __restrict__ S,
                                             u16* __restrict__ D)
{
    __shared__ u16 t[64][68];
    int br = blockIdx.x * 64;
    int bc = blockIdx.y * 64;
    int c = threadIdx.x & 63;
    int r0 = threadIdx.x >> 6;
#pragma unroll
    for (int i = 0; i < 16; ++i) {
        int r = r0 + i * 4;
        t[r][c] = S[(size_t)(br + r) * 2048 + bc + c];
    }
    __syncthreads();
#pragma unroll
    for (int i = 0; i < 16; ++i) {
        int r = r0 + i * 4;
        D[(size_t)(bc + r) * 2048 + br + c] = t[c][r];
    }
}

// ---------------- x fp32 -> bf16 ----------------
__global__ __launch_bounds__(256) void cvt_k(const float* __restrict__ S, u16* __restrict__ D)
{
    int i = (blockIdx.x * 256 + threadIdx.x) * 4;
    float4 v = *(const float4*)(S + i);
    u16 o[4] = {f2bf(v.x), f2bf(v.y), f2bf(v.z), f2bf(v.w)};
    *(ulong1*)(D + i) = *(ulong1*)o;
}

// ---------------- proj dt-columns fp32 -> bf16 [2048][64] ----------------
__global__ __launch_bounds__(256) void cvtdt_k(const float* __restrict__ proj,
                                               u16* __restrict__ pb)
{
    int g = blockIdx.x * 256 + threadIdx.x;
    int m = g >> 4, i = (g & 15) * 4;
    float4 v = *(const float4*)(proj + (size_t)m * 128 + 32 + i);
    u16 o[4] = {f2bf(v.x), f2bf(v.y), f2bf(v.z), f2bf(v.w)};
    *(ulong1*)(pb + (size_t)m * 64 + i) = *(ulong1*)o;
}

// ================= m97-style GEMM: A[M][K] x B[N][K]^T, tile 128x64, BK=64 =========
// MODE 0: G1 split — bn<2048: xs[m][h] via LDS repack; else resT[h][m] direct
// MODE 1: conv gather (+zero-fix), +bias+silu -> u_mh (repack) + uT direct
// MODE 2: plain fp32 [m][n]
template<int MODE>
__global__ __launch_bounds__(256) void gls_k(
    const u16* __restrict__ A, int lda,
    const u16* __restrict__ B, int ldb,
    float* __restrict__ Cf, int ldc,
    u16* __restrict__ Cb0, u16* __restrict__ Cb1,
    const float* __restrict__ bias, int nkt)
{
    __shared__ u16 As[128 * 64];   // [row][64 u16] = 128 B/row, swizzled chunks
    __shared__ u16 Bs[64 * 64];
    const int tid = threadIdx.x;
    const int bm = blockIdx.y * 128;
    const int bn = blockIdx.x * 64;
    const int gofs = (MODE == 1 && bn >= 1024) ? 1024 : 0;
    const int lane = tid & 63, wave = tid >> 6, wm = wave * 32;
    const int m16 = lane & 15, q = lane >> 4;
    floatx4 acc[2][4] = {};

    // staging role: per issue, lane covers (rsub = lane>>3, physical chunk p = lane&7)
    const int rsub = lane >> 3;
    const int pch  = lane & 7;

    for (int kt = 0; kt < nkt; ++kt) {
        const int k0 = kt * 64;
        int tap = 0, ck = k0;
        if (MODE == 1) { tap = k0 >> 10; ck = k0 & 1023; }
        // ---- A tile: 128 rows x 64 k (16 KB), 4 issues
#pragma unroll
        for (int i = 0; i < 4; ++i) {
            int r = i * 32 + wave * 8 + rsub;
            int c = pch ^ (r & 7);           // logical chunk this lane fetches
            const u16* g;
            if (MODE == 1) {
                int rg = bm + r + 2 * tap - 6;   // causal shift (reads below are
                g = A + (size_t)rg * lda + gofs + ck + c * 8;  // in-ws, zero-fixed)
            } else {
                g = A + (size_t)(bm + r) * lda + k0 + c * 8;
            }
            gl_lds16(g, As + i * 2048 + wave * 512);
        }
        // ---- B tile: 64 rows x 64 k (8 KB), 2 issues
#pragma unroll
        for (int i = 0; i < 2; ++i) {
            int r = i * 32 + wave * 8 + rsub;
            int c = pch ^ (r & 7);
            gl_lds16(B + (size_t)(bn + r) * ldb + k0 + c * 8,
                     Bs + i * 2048 + wave * 512);
        }
        if (MODE == 1 && bm == 0) {
            int zr = 6 - 2 * tap;            // rows needing causal zero
            if (zr > 0) {
                asm volatile("s_waitcnt vmcnt(0)" ::: "memory");
                if (tid < 64) {
                    int r = tid >> 3;
                    if (r < zr) *(short8*)(As + r * 64 + (tid & 7) * 8) = short8{};
                }
            }
        }
        __syncthreads();

#pragma unroll
        for (int ks = 0; ks < 2; ++ks) {
            short8 af[2], bfr[4];
#pragma unroll
            for (int ti = 0; ti < 2; ++ti) {
                int r = wm + ti * 16 + m16;
                int p = (ks * 4 + q) ^ (r & 7);
                af[ti] = *(const short8*)(As + r * 64 + p * 8);
            }
#pragma unroll
            for (int tj = 0; tj < 4; ++tj) {
                int r = tj * 16 + m16;
                int p = (ks * 4 + q) ^ (r & 7);
                bfr[tj] = *(const short8*)(Bs + r * 64 + p * 8);
            }
#pragma unroll
            for (int ti = 0; ti < 2; ++ti)
#pragma unroll
                for (int tj = 0; tj < 4; ++tj)
                    acc[ti][tj] = __builtin_amdgcn_mfma_f32_16x16x32_bf16(
                        af[ti], bfr[tj], acc[ti][tj], 0, 0, 0);
        }
        __syncthreads();
    }

    // ---------------- epilogue ----------------
    if (MODE == 2) {
#pragma unroll
        for (int tj = 0; tj < 4; ++tj) {
            int gn = bn + tj * 16 + m16;
#pragma unroll
            for (int ti = 0; ti < 2; ++ti) {
                int gm0 = bm + wm + ti * 16 + q * 4;
#pragma unroll
                for (int r = 0; r < 4; ++r)
                    Cf[(size_t)(gm0 + r) * ldc + gn] = acc[ti][tj][r];
            }
        }
        return;
    }
    if (MODE == 0 && bn >= 2048) {
        // res half -> resT [h][m], contiguous ushort4 along m
#pragma unroll
        for (int tj = 0; tj < 4; ++tj) {
            int gn = bn + tj * 16 + m16;
#pragma unroll
            for (int ti = 0; ti < 2; ++ti) {
                int gm0 = bm + wm + ti * 16 + q * 4;
                ushort4v h;
#pragma unroll
                for (int r = 0; r < 4; ++r) h[r] = f2bf(acc[ti][tj][r]);
                *(ushort4v*)(Cb1 + (size_t)(gn - 2048) * 2048 + gm0) = h;
            }
        }
        return;
    }
    // MODE 0 xs-half or MODE 1: repack [m][h] tile via LDS (As reused, 16 KB)
#pragma unroll
    for (int tj = 0; tj < 4; ++tj) {
        int gn = bn + tj * 16 + m16;
        float bv = (MODE == 1) ? bias[gn] : 0.f;
#pragma unroll
        for (int ti = 0; ti < 2; ++ti) {
            int lr0 = wm + ti * 16 + q * 4;
            ushort4v h;
#pragma unroll
            for (int r = 0; r < 4; ++r) {
                float v = acc[ti][tj][r];
                if (MODE == 1) {
                    v += bv;
                    v = v / (1.f + __expf(-v));
                }
                u16 hv = f2bf(v);
                h[r] = hv;
                As[(lr0 + r) * 64 + tj * 16 + m16] = hv;
            }
            if (MODE == 1)   // uT [h][m] direct
                *(ushort4v*)(Cb1 + (size_t)gn * 2048 + bm + lr0) = h;
        }
    }
    __syncthreads();
    {
        int row = tid >> 1, half = tid & 1;
        u16* gdst = Cb0 + (size_t)(bm + row) * 2048 + bn + half * 32;
        const u16* lsrc = As + row * 64 + half * 32;
#pragma unroll
        for (int i = 0; i < 4; ++i)
            *(short8*)(gdst + i * 8) = *(const short8*)(lsrc + i * 8);
    }
}

// ---------------- G3: proj = u @ W_ssm, split-K MFMA with fp32 atomics ----------------
#define APAD 40
__global__ __launch_bounds__(256) void g3_k(
    const u16* __restrict__ A,      // u_mh bf16 [2048][2048]
    const u16* __restrict__ Bw,     // WT_ssm bf16 [128][2048]
    float* __restrict__ proj)       // [2048][128] fp32, pre-zeroed
{
    __shared__ u16 As[128 * APAD];
    __shared__ u16 Bs[64 * APAD];
    const int tid = threadIdx.x;
    const int bn = blockIdx.x * 64;
    const int bm = blockIdx.y * 128;
    const int kb = blockIdx.z * 512;
    const int lane = tid & 63, wave = tid >> 6, wm = wave * 32;
    const int m16 = lane & 15, q = lane >> 4;
    floatx4 acc[2][4] = {};
    const int ar = tid >> 2, ac = (tid & 3) * 8;

    for (int kt = 0; kt < 16; ++kt) {
        const int k0 = kb + kt * 32;
#pragma unroll
        for (int p = 0; p < 2; ++p) {
            int r = ar + p * 64;
            *(short8*)(As + r * APAD + ac) =
                *(const short8*)(A + (size_t)(bm + r) * 2048 + k0 + ac);
        }
        *(short8*)(Bs + ar * APAD + ac) =
            *(const short8*)(Bw + (size_t)(bn + ar) * 2048 + k0 + ac);
        __syncthreads();

        short8 af[2], bfr[4];
#pragma unroll
        for (int ti = 0; ti < 2; ++ti)
            af[ti] = *(const short8*)(As + (wm + ti * 16 + m16) * APAD + q * 8);
#pragma unroll
        for (int tj = 0; tj < 4; ++tj)
            bfr[tj] = *(const short8*)(Bs + (tj * 16 + m16) * APAD + q * 8);
#pragma unroll
        for (int ti = 0; ti < 2; ++ti)
#pragma unroll
            for (int tj = 0; tj < 4; ++tj)
                acc[ti][tj] = __builtin_amdgcn_mfma_f32_16x16x32_bf16(
                    af[ti], bfr[tj], acc[ti][tj], 0, 0, 0);
        __syncthreads();
    }

#pragma unroll
    for (int tj = 0; tj < 4; ++tj) {
        int gn = bn + tj * 16 + m16;
#pragma unroll
        for (int ti = 0; ti < 2; ++ti)
#pragma unroll
            for (int r = 0; r < 4; ++r) {
                int gm = bm + wm + ti * 16 + q * 4 + r;
                atomicAdd(proj + (size_t)gm * 128 + gn, acc[ti][tj][r]);
            }
    }
}

// ---------------- G4: deltaT = clip(softplus(dtraw @ W_dt + b_dt))^T (K=64) --------
__global__ __launch_bounds__(256) void g4_k(
    const u16* __restrict__ A,      // pb_dt bf16 [2048][64]
    const u16* __restrict__ B,      // WT_dt bf16 [2048][64]
    const float* __restrict__ bias,
    float* __restrict__ Cf)         // deltaT fp32 [h][m], ld 2048
{
    __shared__ u16 As[128 * APAD];
    __shared__ u16 Bs[64 * APAD];
    const int tid = threadIdx.x;
    const int bm = blockIdx.y * 128;
    const int bn = blockIdx.x * 64;
    const int lane = tid & 63, wave = tid >> 6, wm = wave * 32;
    const int m16 = lane & 15, q = lane >> 4;
    floatx4 acc[2][4] = {};
    const int ar = tid >> 2, ac = (tid & 3) * 8;

    for (int kt = 0; kt < 2; ++kt) {
        const int k0 = kt * 32;
#pragma unroll
        for (int p = 0; p < 2; ++p) {
            int r = ar + p * 64;
            *(short8*)(As + r * APAD + ac) =
                *(const short8*)(A + (size_t)(bm + r) * 64 + k0 + ac);
        }
        *(short8*)(Bs + ar * APAD + ac) =
            *(const short8*)(B + (size_t)(bn + ar) * 64 + k0 + ac);
        __syncthreads();
        short8 af[2], bfr[4];
#pragma unroll
        for (int ti = 0; ti < 2; ++ti)
            af[ti] = *(const short8*)(As + (wm + ti * 16 + m16) * APAD + q * 8);
#pragma unroll
        for (int tj = 0; tj < 4; ++tj)
            bfr[tj] = *(const short8*)(Bs + (tj * 16 + m16) * APAD + q * 8);
#pragma unroll
        for (int ti = 0; ti < 2; ++ti)
#pragma unroll
            for (int tj = 0; tj < 4; ++tj)
                acc[ti][tj] = __builtin_amdgcn_mfma_f32_16x16x32_bf16(
                    af[ti], bfr[tj], acc[ti][tj], 0, 0, 0);
        __syncthreads();
    }
#pragma unroll
    for (int tj = 0; tj < 4; ++tj) {
        int gn = bn + tj * 16 + m16;
        float bv = bias[gn];
#pragma unroll
        for (int ti = 0; ti < 2; ++ti) {
            int gm0 = bm + wm + ti * 16 + q * 4;
            float t[4];
#pragma unroll
            for (int r = 0; r < 4; ++r) {
                float v = acc[ti][tj][r] + bv;
                v = (v > 15.f) ? v : log1pf(__expf(v));
                t[r] = fminf(fmaxf(v, 0.001f), 0.1f);
            }
            *(float4*)(Cf + (size_t)gn * 2048 + gm0) =
                make_float4(t[0], t[1], t[2], t[3]);
        }
    }
}

// ---------------- scan: 1 block per h, both batches per lane ----------------
__global__ __launch_bounds__(512) void scan4_k(
    const float* __restrict__ deltaT,  // [2048 h][2048 m]
    const u16* __restrict__ uT,        // [2048 h][2048 m] bf16
    const float* __restrict__ proj,    // [2048 m][128] (B|C|dtraw|pad)
    const float* __restrict__ A_log,
    const float* __restrict__ Dvec,
    const u16* __restrict__ resT,      // [2048 h][2048 m] bf16
    u16* __restrict__ zT)              // [2048 h][2048 m] bf16
{
    __shared__ float lP[2][32][16], lS[2][32][16], lI[2][32][16];
    __shared__ float yrow[2048];
    const int h = blockIdx.x;
    const int tid = threadIdx.x;
    const int n = tid & 15;
    const int c = tid >> 4;
    const int l0 = c * 32;

    const float Ahn = -__expf(A_log[h * 16 + n]);
    const float* drow = deltaT + (size_t)h * 2048;
    const u16*   urow = uT     + (size_t)h * 2048;

    float s0 = 0.f, P0 = 1.f, s1 = 0.f, P1 = 1.f;
    for (int j = 0; j < 32; ++j) {
        int l = l0 + j;
        float2 dtv = *(const float2*)(drow + 2 * l);
        u32 uv = *(const u32*)(urow + 2 * l);
        float uu0 = __uint_as_float(uv << 16);
        float uu1 = __uint_as_float(uv & 0xffff0000u);
        float B0 = proj[(size_t)(2 * l) * 128 + n];
        float B1 = proj[(size_t)(2 * l + 1) * 128 + n];
        float e0 = __expf(dtv.x * Ahn);
        float e1 = __expf(dtv.y * Ahn);
        s0 = fmaf(e0, s0, dtv.x * uu0 * B0);
        s1 = fmaf(e1, s1, dtv.y * uu1 * B1);
        P0 *= e0;
        P1 *= e1;
    }
    lP[0][c][n] = P0; lS[0][c][n] = s0;
    lP[1][c][n] = P1; lS[1][c][n] = s1;
    __syncthreads();
    if (tid < 32) {
        int bb = tid >> 4, nn = tid & 15;
        float X = 0.f;
#pragma unroll
        for (int cc = 0; cc < 32; ++cc) {
            lI[bb][cc][nn] = X;
            X = fmaf(lP[bb][cc][nn], X, lS[bb][cc][nn]);
        }
    }
    __syncthreads();

    s0 = lI[0][c][n];
    s1 = lI[1][c][n];
    const float Dh = Dvec[h];
    for (int j = 0; j < 32; ++j) {
        int l = l0 + j;
        float2 dtv = *(const float2*)(drow + 2 * l);
        u32 uv = *(const u32*)(urow + 2 * l);
        float uu0 = __uint_as_float(uv << 16);
        float uu1 = __uint_as_float(uv & 0xffff0000u);
        float B0 = proj[(size_t)(2 * l) * 128 + n];
        float B1 = proj[(size_t)(2 * l + 1) * 128 + n];
        float C0 = proj[(size_t)(2 * l) * 128 + 16 + n];
        float C1 = proj[(size_t)(2 * l + 1) * 128 + 16 + n];
        float e0 = __expf(dtv.x * Ahn);
        float e1 = __expf(dtv.y * Ahn);
        s0 = fmaf(e0, s0, dtv.x * uu0 * B0);
        s1 = fmaf(e1, s1, dtv.y * uu1 * B1);
        float v0 = C0 * s0;
        float v1 = C1 * s1;
        v0 += __shfl_xor(v0, 1, 16);
        v0 += __shfl_xor(v0, 2, 16);
        v0 += __shfl_xor(v0, 4, 16);
        v0 += __shfl_xor(v0, 8, 16);
        v1 += __shfl_xor(v1, 1, 16);
        v1 += __shfl_xor(v1, 2, 16);
        v1 += __shfl_xor(v1, 4, 16);
        v1 += __shfl_xor(v1, 8, 16);
        if (n == 0) {
            yrow[2 * l]     = v0 + uu0 * Dh;
            yrow[2 * l + 1] = v1 + uu1 * Dh;
        }
    }
    __syncthreads();
    {
        int t0 = tid * 4;
        ushort4v rv = *(const ushort4v*)(resT + (size_t)h * 2048 + t0);
        u16 o[4];
#pragma unroll
        for (int i = 0; i < 4; ++i) {
            float r = bf2f(rv[i]);
            float y = yrow[t0 + i];
            o[i] = f2bf(y * (r / (1.f + __expf(-r))));
        }
        *(ulong1*)(zT + (size_t)h * 2048 + t0) = *(ulong1*)o;
    }
}

extern "C" void kernel_launch(void* const* d_in, const int* in_sizes, int n_in,
                              void* d_out, int out_size, void* d_ws, size_t ws_size,
                              hipStream_t stream)
{
    const float* x      = (const float*)d_in[0];
    const float* W_in   = (const float*)d_in[1];
    const float* W_conv = (const float*)d_in[2];
    const float* b_conv = (const float*)d_in[3];
    const float* A_log  = (const float*)d_in[4];
    const float* Dv     = (const float*)d_in[5];
    const float* W_ssm  = (const float*)d_in[6];
    const float* W_dt   = (const float*)d_in[7];
    const float* b_dt   = (const float*)d_in[8];
    const float* W_out  = (const float*)d_in[9];
    float* out = (float*)d_out;

    // ws layout (~57 MB), lifetime-aliased:
    //  0M : xb bf16 [2048][1024] (..G1) -> projb fp32 [2048][128] (G3..scan), pb_dt @2M
    //  4M : WT_in (..G1) -> u_mh bf16 [2048][2048] (conv..G3) -> z_mh (TZ..G5)
    //  12M: xsbf bf16 [m][h] (G1..conv) -> zT bf16 [h][m] (scan..TZ)
    //  20M: resT bf16 [h][m] (G1..scan)
    //  28M: WT_cv (..conv) -> deltaT fp32 [h][m] (G4..scan)
    //  44M: uT bf16 [h][m] (conv..scan)
    //  52M: WT_out (..G5)   56M: WT_ssm (..G3)   56.5M: WT_dt (..G4)
    char* wsc = (char*)d_ws;
    u16*   xb     = (u16*)wsc;
    float* projb  = (float*)wsc;
    u16*   pb_dt  = (u16*)(wsc + (2u << 20));
    u16*   WT_in  = (u16*)(wsc + (4u << 20));
    u16*   u_mh   = (u16*)(wsc + (4u << 20));
    u16*   z_mh   = (u16*)(wsc + (4u << 20));
    u16*   xsbf   = (u16*)(wsc + (12u << 20));
    u16*   zT     = xsbf;
    u16*   resT   = (u16*)(wsc + (20u << 20));
    u16*   WT_cv  = (u16*)(wsc + (28u << 20));
    float* deltaT = (float*)(wsc + (28u << 20));
    u16*   uT     = (u16*)(wsc + (44u << 20));
    u16*   WT_out = (u16*)(wsc + (52u << 20));
    u16*   WT_ssm = (u16*)(wsc + (56u << 20));
    u16*   WT_dt  = (u16*)(wsc + (56u << 20) + (512u << 10));

    dim3 blk(256);

    // T: transposes + converts
    trans_k<<<dim3(64, 32), blk, 0, stream>>>(W_conv, WT_cv, 4096, 2048);
    trans_k<<<dim3(16, 64), blk, 0, stream>>>(W_in, WT_in, 1024, 4096);
    trans_k<<<dim3(32, 16), blk, 0, stream>>>(W_out, WT_out, 2048, 1024);
    trans_k<<<dim3(32, 2),  blk, 0, stream>>>(W_ssm, WT_ssm, 2048, 96);
    trans_k<<<dim3(1, 32),  blk, 0, stream>>>(W_dt, WT_dt, 64, 2048);
    cvt_k<<<dim3(2048), blk, 0, stream>>>(x, xb);

    // G1: xs[m][ch] | resT[h][m]
    gls_k<0><<<dim3(64, 16), blk, 0, stream>>>(
        xb, 1024, WT_in, 1024, nullptr, 0, xsbf, resT, nullptr, 16);

    // C: conv -> u_mh + uT
    gls_k<1><<<dim3(32, 16), blk, 0, stream>>>(
        xsbf, 2048, WT_cv, 4096, nullptr, 0, u_mh, uT, b_conv, 64);

    // G3: proj (split-K atomics)
    hipMemsetAsync(projb, 0, 2048 * 128 * sizeof(float), stream);
    g3_k<<<dim3(2, 16, 4), blk, 0, stream>>>(u_mh, WT_ssm, projb);

    // dt columns -> bf16
    cvtdt_k<<<dim3(128), blk, 0, stream>>>(projb, pb_dt);

    // G4: deltaT
    g4_k<<<dim3(32, 16), blk, 0, stream>>>(pb_dt, WT_dt, b_dt, deltaT);

    // S: scan -> zT
    scan4_k<<<dim3(2048), dim3(512), 0, stream>>>(
        deltaT, uT, projb, A_log, Dv, resT, zT);

    // TZ: zT -> z_mh
    tbf_k<<<dim3(32, 32), blk, 0, stream>>>(zT, z_mh);

    // G5: out = z_mh @ WT_out^T
    gls_k<2><<<dim3(16, 16), blk, 0, stream>>>(
        z_mh, 2048, WT_out, 2048, out, 1024, nullptr, nullptr, nullptr, 32);
}